// Round 2
// baseline (564.725 us; speedup 1.0000x reference)
//
#include <hip/hip_runtime.h>

// ---------- CSR build ----------
__global__ void k_init_deg(int* __restrict__ deg, int N) {
    int i = blockIdx.x * blockDim.x + threadIdx.x;
    if (i < N) deg[i] = 1;            // self-loop
}

__global__ void k_count(const int* __restrict__ dst, int E, int* __restrict__ deg) {
    int e = blockIdx.x * blockDim.x + threadIdx.x;
    if (e < E) atomicAdd(&deg[dst[e]], 1);
}

// block-wise exclusive scan of (deg-1) = in-degree (CSR holds real edges only)
__global__ void k_scan1(const int* __restrict__ deg, int* __restrict__ row_ptr,
                        int* __restrict__ bsum, int N) {
    __shared__ int s[256];
    int t = threadIdx.x;
    int i = blockIdx.x * 256 + t;
    int v = (i < N) ? (deg[i] - 1) : 0;
    s[t] = v; __syncthreads();
    for (int off = 1; off < 256; off <<= 1) {
        int x = (t >= off) ? s[t - off] : 0;
        __syncthreads();
        s[t] += x;
        __syncthreads();
    }
    if (i < N) row_ptr[i] = s[t] - v;          // exclusive within block
    if (t == 255) bsum[blockIdx.x] = s[255];   // block total
}

__global__ void k_scan2(int* __restrict__ bsum, int nb) {  // nb <= 256
    __shared__ int s[256];
    int t = threadIdx.x;
    int v = (t < nb) ? bsum[t] : 0;
    s[t] = v; __syncthreads();
    for (int off = 1; off < 256; off <<= 1) {
        int x = (t >= off) ? s[t - off] : 0;
        __syncthreads();
        s[t] += x;
        __syncthreads();
    }
    if (t < nb) bsum[t] = s[t] - v;            // exclusive
}

__global__ void k_scan3(const int* __restrict__ deg, int* __restrict__ row_ptr,
                        const int* __restrict__ bsum, int* __restrict__ cursor,
                        float* __restrict__ dinv, int N, int E) {
    int i = blockIdx.x * 256 + threadIdx.x;
    if (i < N) {
        int rp = row_ptr[i] + bsum[blockIdx.x];
        row_ptr[i] = rp;
        cursor[i]  = rp;
        dinv[i]    = rsqrtf((float)deg[i]);    // deg >= 1 always
    }
    if (i == 0) row_ptr[N] = E;
}

__global__ void k_fill(const int* __restrict__ src, const int* __restrict__ dst, int E,
                       int* __restrict__ cursor, int* __restrict__ csr) {
    int e = blockIdx.x * blockDim.x + threadIdx.x;
    if (e < E) {
        int p = atomicAdd(&cursor[dst[e]], 1);
        csr[p] = src[e];
    }
}

// ---------- GEMM: M[i][c] = (sum_k A[i][k] * W[k][c]) * dinv[i] ----------
// block = 256 threads, 32 rows/block, each thread: 16 rows x 1 col
__global__ __launch_bounds__(256) void k_gemm128(const float* __restrict__ A,
                                                 const float* __restrict__ W,
                                                 const float* __restrict__ dinv,
                                                 float* __restrict__ M, int N) {
    __shared__ __align__(16) float Wl[128 * 128];  // 64 KB
    __shared__ __align__(16) float Al[32 * 128];   // 16 KB
    int t = threadIdx.x;

    // W (128x128 fp32) -> LDS, row-major [k][c]; 4096 float4
    {
        const float4* Wp = (const float4*)W;
        for (int i = 0; i < 16; i++) {
            int j = t + i * 256;
            ((float4*)Wl)[j] = Wp[j];
        }
    }

    int row0 = blockIdx.x * 32;
    int tileElems = (N - row0 < 32 ? N - row0 : 32) * 128;
    {
        const float4* Ap = (const float4*)(A + (size_t)row0 * 128);
        for (int i = 0; i < 4; i++) {
            int idx = t + i * 256;                // f4 index within tile (< 1024)
            float4 v;
            if (4 * idx < tileElems) v = Ap[idx];
            else { v.x = v.y = v.z = v.w = 0.f; }
            ((float4*)Al)[idx] = v;
        }
    }
    __syncthreads();

    int c  = t & 127;
    int rg = t >> 7;                              // 0..1 (wave-uniform)
    const float* Arow = Al + rg * 16 * 128;

    float acc[16];
#pragma unroll
    for (int r = 0; r < 16; r++) acc[r] = 0.f;

    for (int k = 0; k < 128; k += 4) {
        float w0 = Wl[(k + 0) * 128 + c];
        float w1 = Wl[(k + 1) * 128 + c];
        float w2 = Wl[(k + 2) * 128 + c];
        float w3 = Wl[(k + 3) * 128 + c];
#pragma unroll
        for (int r = 0; r < 16; r++) {
            float4 a = *(const float4*)(Arow + r * 128 + k);  // wave-uniform broadcast
            acc[r] = fmaf(a.x, w0, fmaf(a.y, w1, fmaf(a.z, w2, fmaf(a.w, w3, acc[r]))));
        }
    }

#pragma unroll
    for (int r = 0; r < 16; r++) {
        int gr = row0 + rg * 16 + r;
        if (gr < N) M[(size_t)gr * 128 + c] = acc[r] * dinv[gr];
    }
}

// ---------- gather: H[v] = relu(dinv[v]*(m[v] + sum_{u->v} m[u]) + b) ----------
// one wave per node; lane handles features (2*lane, 2*lane+1); 512B per node row
__global__ __launch_bounds__(256) void k_gather(const float* __restrict__ M,
                                                const int* __restrict__ csr,
                                                const int* __restrict__ row_ptr,
                                                const float* __restrict__ dinv,
                                                const float* __restrict__ bias,
                                                float* __restrict__ H, int N) {
    int w    = (blockIdx.x << 2) + (threadIdx.x >> 6);
    int lane = threadIdx.x & 63;
    if (w >= N) return;

    float2 acc = ((const float2*)(M + (size_t)w * 128))[lane];  // self term
    int s0 = row_ptr[w], s1 = row_ptr[w + 1];

    for (int base = s0; base < s1; base += 64) {
        int n = s1 - base; if (n > 64) n = 64;
        int u = (lane < n) ? csr[base + lane] : 0;
        int j = 0;
        for (; j + 4 <= n; j += 4) {
            int u0 = __shfl(u, j), u1 = __shfl(u, j + 1);
            int u2 = __shfl(u, j + 2), u3 = __shfl(u, j + 3);
            float2 t0 = ((const float2*)(M + (size_t)u0 * 128))[lane];
            float2 t1 = ((const float2*)(M + (size_t)u1 * 128))[lane];
            float2 t2 = ((const float2*)(M + (size_t)u2 * 128))[lane];
            float2 t3 = ((const float2*)(M + (size_t)u3 * 128))[lane];
            acc.x += (t0.x + t1.x) + (t2.x + t3.x);
            acc.y += (t0.y + t1.y) + (t2.y + t3.y);
        }
        for (; j < n; j++) {
            int uj = __shfl(u, j);
            float2 tj = ((const float2*)(M + (size_t)uj * 128))[lane];
            acc.x += tj.x; acc.y += tj.y;
        }
    }

    float dv = dinv[w];
    float bx = bias[2 * lane], by = bias[2 * lane + 1];
    float ox = fmaxf(fmaf(dv, acc.x, bx), 0.f);
    float oy = fmaxf(fmaf(dv, acc.y, by), 0.f);
    ((float2*)H)[(size_t)w * 64 + lane] = make_float2(ox, oy);
}

// ---------- classifier: out[i][c] = sum_k h[i][k]*Wc[k][c] + bc[c], c<40 ----------
// block = 256 threads, 64 rows/block, cols padded to 64; thread: 16 rows x 1 col
__global__ __launch_bounds__(256) void k_gemm40(const float* __restrict__ A,
                                                const float* __restrict__ Wc,
                                                const float* __restrict__ bc,
                                                float* __restrict__ out, int N) {
    __shared__ __align__(16) float Wl[128 * 64];  // 32 KB (cols padded 40->64)
    __shared__ __align__(16) float Al[64 * 128];  // 32 KB
    int t = threadIdx.x;

    for (int i = 0; i < 32; i++) Wl[t + i * 256] = 0.f;   // zero padded cols
    __syncthreads();

    {   // Wc is 128x40: elem j=(k*40+c) -> Wl[k*64+c]
        for (int i = 0; i < 20; i++) {
            int j = t + i * 256;                  // < 5120
            int k = j / 40, c = j - 40 * k;
            Wl[k * 64 + c] = Wc[j];
        }
    }

    int row0 = blockIdx.x * 64;
    int tileElems = (N - row0 < 64 ? N - row0 : 64) * 128;
    {
        const float4* Ap = (const float4*)(A + (size_t)row0 * 128);
        for (int i = 0; i < 8; i++) {
            int idx = t + i * 256;                // f4 index (< 2048)
            float4 v;
            if (4 * idx < tileElems) v = Ap[idx];
            else { v.x = v.y = v.z = v.w = 0.f; }
            ((float4*)Al)[idx] = v;
        }
    }
    __syncthreads();

    int c  = t & 63;
    int rg = t >> 6;                              // 0..3 (wave-uniform)
    const float* Arow = Al + rg * 16 * 128;

    float acc[16];
#pragma unroll
    for (int r = 0; r < 16; r++) acc[r] = 0.f;

    for (int k = 0; k < 128; k += 4) {
        float w0 = Wl[(k + 0) * 64 + c];
        float w1 = Wl[(k + 1) * 64 + c];
        float w2 = Wl[(k + 2) * 64 + c];
        float w3 = Wl[(k + 3) * 64 + c];
#pragma unroll
        for (int r = 0; r < 16; r++) {
            float4 a = *(const float4*)(Arow + r * 128 + k);
            acc[r] = fmaf(a.x, w0, fmaf(a.y, w1, fmaf(a.z, w2, fmaf(a.w, w3, acc[r]))));
        }
    }

    if (c < 40) {
        float b = bc[c];
#pragma unroll
        for (int r = 0; r < 16; r++) {
            int gr = row0 + rg * 16 + r;
            if (gr < N) out[(size_t)gr * 40 + c] = acc[r] + b;
        }
    }
}

// ---------- launch ----------
extern "C" void kernel_launch(void* const* d_in, const int* in_sizes, int n_in,
                              void* d_out, int out_size, void* d_ws, size_t ws_size,
                              hipStream_t stream) {
    const float* x  = (const float*)d_in[0];
    const int*   ei = (const int*)d_in[1];
    const float* W1 = (const float*)d_in[2];
    const float* b1 = (const float*)d_in[3];
    const float* W2 = (const float*)d_in[4];
    const float* b2 = (const float*)d_in[5];
    const float* W3 = (const float*)d_in[6];
    const float* b3 = (const float*)d_in[7];
    const float* Wc = (const float*)d_in[8];
    const float* bc = (const float*)d_in[9];

    const int N = in_sizes[0] / 128;   // 50000
    const int E = in_sizes[1] / 2;     // 800000
    const int* src = ei;
    const int* dst = ei + E;

    // workspace carve-out (~30 MB)
    char* ws = (char*)d_ws;
    size_t off = 0;
    auto alloc = [&](size_t bytes) -> void* {
        void* p = ws + off;
        off = (off + bytes + 255) & ~(size_t)255;
        return p;
    };
    float* Mbuf    = (float*)alloc((size_t)N * 128 * 4);
    float* dinv    = (float*)alloc((size_t)N * 4);
    int*   deg     = (int*)alloc((size_t)N * 4);
    int*   row_ptr = (int*)alloc((size_t)(N + 1) * 4);
    int*   cursor  = (int*)alloc((size_t)N * 4);
    int*   csr     = (int*)alloc((size_t)E * 4);
    int*   bsum    = (int*)alloc(256 * 4);

    float* out  = (float*)d_out;               // logits [N,40]
    float* hbuf = out + (size_t)N * 40;        // h region [N,128] — reused as H for all layers

    const int nb = (N + 255) / 256;   // 196 (<=256, required by k_scan2)
    const int eb = (E + 255) / 256;

    k_init_deg<<<nb, 256, 0, stream>>>(deg, N);
    k_count<<<eb, 256, 0, stream>>>(dst, E, deg);
    k_scan1<<<nb, 256, 0, stream>>>(deg, row_ptr, bsum, N);
    k_scan2<<<1, 256, 0, stream>>>(bsum, nb);
    k_scan3<<<nb, 256, 0, stream>>>(deg, row_ptr, bsum, cursor, dinv, N, E);
    k_fill<<<eb, 256, 0, stream>>>(src, dst, E, cursor, csr);

    const int gb  = (N + 31) / 32;    // gemm128 blocks
    const int gab = (N + 3) / 4;      // gather blocks (4 waves/block)

    // layer 1: x -> Mbuf -> hbuf
    k_gemm128<<<gb, 256, 0, stream>>>(x, W1, dinv, Mbuf, N);
    k_gather<<<gab, 256, 0, stream>>>(Mbuf, csr, row_ptr, dinv, b1, hbuf, N);
    // layer 2
    k_gemm128<<<gb, 256, 0, stream>>>(hbuf, W2, dinv, Mbuf, N);
    k_gather<<<gab, 256, 0, stream>>>(Mbuf, csr, row_ptr, dinv, b2, hbuf, N);
    // layer 3: h3 written straight into d_out h-region
    k_gemm128<<<gb, 256, 0, stream>>>(hbuf, W3, dinv, Mbuf, N);
    k_gather<<<gab, 256, 0, stream>>>(Mbuf, csr, row_ptr, dinv, b3, hbuf, N);
    // classifier reads h3 from d_out
    k_gemm40<<<(N + 63) / 64, 256, 0, stream>>>(hbuf, Wc, bc, out, N);
}

// Round 3
// 501.709 us; speedup vs baseline: 1.1256x; 1.1256x over previous
//
#include <hip/hip_runtime.h>

// ---------- CSR build ----------
__global__ void k_init_deg(int* __restrict__ deg, int N) {
    int i = blockIdx.x * blockDim.x + threadIdx.x;
    if (i < N) deg[i] = 1;            // self-loop
}

__global__ void k_count(const int* __restrict__ dst, int E, int* __restrict__ deg) {
    int e = blockIdx.x * blockDim.x + threadIdx.x;
    if (e < E) atomicAdd(&deg[dst[e]], 1);
}

// block-wise exclusive scan of (deg-1) = in-degree (CSR holds real edges only)
__global__ void k_scan1(const int* __restrict__ deg, int* __restrict__ row_ptr,
                        int* __restrict__ bsum, int N) {
    __shared__ int s[256];
    int t = threadIdx.x;
    int i = blockIdx.x * 256 + t;
    int v = (i < N) ? (deg[i] - 1) : 0;
    s[t] = v; __syncthreads();
    for (int off = 1; off < 256; off <<= 1) {
        int x = (t >= off) ? s[t - off] : 0;
        __syncthreads();
        s[t] += x;
        __syncthreads();
    }
    if (i < N) row_ptr[i] = s[t] - v;          // exclusive within block
    if (t == 255) bsum[blockIdx.x] = s[255];   // block total
}

__global__ void k_scan2(int* __restrict__ bsum, int nb) {  // nb <= 256
    __shared__ int s[256];
    int t = threadIdx.x;
    int v = (t < nb) ? bsum[t] : 0;
    s[t] = v; __syncthreads();
    for (int off = 1; off < 256; off <<= 1) {
        int x = (t >= off) ? s[t - off] : 0;
        __syncthreads();
        s[t] += x;
        __syncthreads();
    }
    if (t < nb) bsum[t] = s[t] - v;            // exclusive
}

__global__ void k_scan3(const int* __restrict__ deg, int* __restrict__ row_ptr,
                        const int* __restrict__ bsum, int* __restrict__ cursor,
                        float* __restrict__ dinv, int N, int E) {
    int i = blockIdx.x * 256 + threadIdx.x;
    if (i < N) {
        int rp = row_ptr[i] + bsum[blockIdx.x];
        row_ptr[i] = rp;
        cursor[i]  = rp;
        dinv[i]    = rsqrtf((float)deg[i]);    // deg >= 1 always
    }
    if (i == 0) row_ptr[N] = E;
}

__global__ void k_fill(const int* __restrict__ src, const int* __restrict__ dst, int E,
                       int* __restrict__ cursor, int* __restrict__ csr) {
    int e = blockIdx.x * blockDim.x + threadIdx.x;
    if (e < E) {
        int p = atomicAdd(&cursor[dst[e]], 1);
        csr[p] = src[e];
    }
}

// ---------- GEMM: M[i][c] = (sum_k A[i][k] * W[k][c]) * dinv[i] ----------
// Register-tiled: BM=64, BN=128, BK=32 double-buffered. 256 threads, each
// computes a 4x8 micro-tile: per k-step 3x ds_read_b128 vs 32 FMAs.
// A staged transposed [k][row] (col-of-4-rows = one b128, broadcast 16-way).
// W rows staggered +4 words per 32 cols so wave's 16 b128 addrs cover all
// 32 banks (2-way aliasing = free).
#define WS_STRIDE 144   // 128 + 4*4 stagger
__global__ __launch_bounds__(256) void k_gemm128(const float* __restrict__ A,
                                                 const float* __restrict__ W,
                                                 const float* __restrict__ dinv,
                                                 float* __restrict__ M, int N) {
    __shared__ __align__(16) float As[2][32 * 64];        // 16 KB
    __shared__ __align__(16) float Ws[2][32 * WS_STRIDE]; // 36.9 KB
    int t = threadIdx.x;
    int row0 = blockIdx.x * 64;

    // staging indices
    int arow = t & 63;              // A row within tile
    int akk  = (t >> 6) * 8;        // starting k within stage (0,8,16,24)
    bool avalid = (row0 + arow) < N;
    const float* Aptr = A + (size_t)(avalid ? (row0 + arow) : 0) * 128;

    // compute indices
    int rg = t >> 4;                // 0..15 -> rows rg*4..rg*4+3
    int cg = t & 15;                // 0..15 -> cols cg*8..cg*8+7
    int wofs = cg * 8 + ((cg >> 2) << 2);   // staggered col offset

    float4 are0, are1, wre[4];
    const float4* Wp = (const float4*)W;

    auto load_stage = [&](int s) {
        int k0 = s * 32;
        if (avalid) {
            are0 = *(const float4*)(Aptr + k0 + akk);
            are1 = *(const float4*)(Aptr + k0 + akk + 4);
        } else {
            are0 = make_float4(0.f, 0.f, 0.f, 0.f);
            are1 = are0;
        }
#pragma unroll
        for (int i = 0; i < 4; i++) {
            int j = t + i * 256;                 // float4 idx within stage, <1024
            wre[i] = Wp[(size_t)k0 * 32 + j];
        }
    };
    auto store_stage = [&](int b) {
        float* ap = (float*)&are0;
#pragma unroll
        for (int j = 0; j < 4; j++) As[b][(akk + j) * 64 + arow] = ap[j];
        ap = (float*)&are1;
#pragma unroll
        for (int j = 0; j < 4; j++) As[b][(akk + 4 + j) * 64 + arow] = ap[j];
#pragma unroll
        for (int i = 0; i < 4; i++) {
            int j = t + i * 256;
            int k = j >> 5, c4 = (j & 31) * 4;
            *(float4*)&Ws[b][k * WS_STRIDE + c4 + ((c4 >> 5) << 2)] = wre[i];
        }
    };

    float acc[4][8];
#pragma unroll
    for (int i = 0; i < 4; i++)
#pragma unroll
        for (int j = 0; j < 8; j++) acc[i][j] = 0.f;

    load_stage(0);
    store_stage(0);
    __syncthreads();

    for (int s = 0; s < 4; s++) {
        int b = s & 1;
        if (s < 3) load_stage(s + 1);
#pragma unroll 8
        for (int k = 0; k < 32; k++) {
            float4 a  = *(const float4*)&As[b][k * 64 + rg * 4];
            float4 w0 = *(const float4*)&Ws[b][k * WS_STRIDE + wofs];
            float4 w1 = *(const float4*)&Ws[b][k * WS_STRIDE + wofs + 4];
            float av[4] = {a.x, a.y, a.z, a.w};
#pragma unroll
            for (int i = 0; i < 4; i++) {
                acc[i][0] = fmaf(av[i], w0.x, acc[i][0]);
                acc[i][1] = fmaf(av[i], w0.y, acc[i][1]);
                acc[i][2] = fmaf(av[i], w0.z, acc[i][2]);
                acc[i][3] = fmaf(av[i], w0.w, acc[i][3]);
                acc[i][4] = fmaf(av[i], w1.x, acc[i][4]);
                acc[i][5] = fmaf(av[i], w1.y, acc[i][5]);
                acc[i][6] = fmaf(av[i], w1.z, acc[i][6]);
                acc[i][7] = fmaf(av[i], w1.w, acc[i][7]);
            }
        }
        if (s < 3) {
            store_stage((s + 1) & 1);
            __syncthreads();
        }
    }

#pragma unroll
    for (int i = 0; i < 4; i++) {
        int gr = row0 + rg * 4 + i;
        if (gr < N) {
            float dv = dinv[gr];
            float4 o0 = make_float4(acc[i][0] * dv, acc[i][1] * dv,
                                    acc[i][2] * dv, acc[i][3] * dv);
            float4 o1 = make_float4(acc[i][4] * dv, acc[i][5] * dv,
                                    acc[i][6] * dv, acc[i][7] * dv);
            *(float4*)&M[(size_t)gr * 128 + cg * 8]     = o0;
            *(float4*)&M[(size_t)gr * 128 + cg * 8 + 4] = o1;
        }
    }
}

// ---------- gather: H[v] = relu(dinv[v]*(m[v] + sum_{u->v} m[u]) + b) ----------
// one wave per node; lane handles features (2*lane, 2*lane+1); 512B per node row
__global__ __launch_bounds__(256) void k_gather(const float* __restrict__ M,
                                                const int* __restrict__ csr,
                                                const int* __restrict__ row_ptr,
                                                const float* __restrict__ dinv,
                                                const float* __restrict__ bias,
                                                float* __restrict__ H, int N) {
    int w    = (blockIdx.x << 2) + (threadIdx.x >> 6);
    int lane = threadIdx.x & 63;
    if (w >= N) return;

    float2 acc = ((const float2*)(M + (size_t)w * 128))[lane];  // self term
    int s0 = row_ptr[w], s1 = row_ptr[w + 1];

    for (int base = s0; base < s1; base += 64) {
        int n = s1 - base; if (n > 64) n = 64;
        int u = (lane < n) ? csr[base + lane] : 0;
        int j = 0;
        for (; j + 4 <= n; j += 4) {
            int u0 = __shfl(u, j), u1 = __shfl(u, j + 1);
            int u2 = __shfl(u, j + 2), u3 = __shfl(u, j + 3);
            float2 t0 = ((const float2*)(M + (size_t)u0 * 128))[lane];
            float2 t1 = ((const float2*)(M + (size_t)u1 * 128))[lane];
            float2 t2 = ((const float2*)(M + (size_t)u2 * 128))[lane];
            float2 t3 = ((const float2*)(M + (size_t)u3 * 128))[lane];
            acc.x += (t0.x + t1.x) + (t2.x + t3.x);
            acc.y += (t0.y + t1.y) + (t2.y + t3.y);
        }
        for (; j < n; j++) {
            int uj = __shfl(u, j);
            float2 tj = ((const float2*)(M + (size_t)uj * 128))[lane];
            acc.x += tj.x; acc.y += tj.y;
        }
    }

    float dv = dinv[w];
    float bx = bias[2 * lane], by = bias[2 * lane + 1];
    float ox = fmaxf(fmaf(dv, acc.x, bx), 0.f);
    float oy = fmaxf(fmaf(dv, acc.y, by), 0.f);
    ((float2*)H)[(size_t)w * 64 + lane] = make_float2(ox, oy);
}

// ---------- classifier: out[i][c] = sum_k h[i][k]*Wc[k][c] + bc[c], c<40 ----------
// block = 256 threads, 64 rows/block, cols padded to 64; thread: 16 rows x 1 col
__global__ __launch_bounds__(256) void k_gemm40(const float* __restrict__ A,
                                                const float* __restrict__ Wc,
                                                const float* __restrict__ bc,
                                                float* __restrict__ out, int N) {
    __shared__ __align__(16) float Wl[128 * 64];  // 32 KB (cols padded 40->64)
    __shared__ __align__(16) float Al[64 * 128];  // 32 KB
    int t = threadIdx.x;

    for (int i = 0; i < 32; i++) Wl[t + i * 256] = 0.f;   // zero padded cols
    __syncthreads();

    {   // Wc is 128x40: elem j=(k*40+c) -> Wl[k*64+c]
        for (int i = 0; i < 20; i++) {
            int j = t + i * 256;                  // < 5120
            int k = j / 40, c = j - 40 * k;
            Wl[k * 64 + c] = Wc[j];
        }
    }

    int row0 = blockIdx.x * 64;
    int tileElems = (N - row0 < 64 ? N - row0 : 64) * 128;
    {
        const float4* Ap = (const float4*)(A + (size_t)row0 * 128);
        for (int i = 0; i < 8; i++) {
            int idx = t + i * 256;                // f4 index (< 2048)
            float4 v;
            if (4 * idx < tileElems) v = Ap[idx];
            else { v.x = v.y = v.z = v.w = 0.f; }
            ((float4*)Al)[idx] = v;
        }
    }
    __syncthreads();

    int c  = t & 63;
    int rg = t >> 6;                              // 0..3 (wave-uniform)
    const float* Arow = Al + rg * 16 * 128;

    float acc[16];
#pragma unroll
    for (int r = 0; r < 16; r++) acc[r] = 0.f;

    for (int k = 0; k < 128; k += 4) {
        float w0 = Wl[(k + 0) * 64 + c];
        float w1 = Wl[(k + 1) * 64 + c];
        float w2 = Wl[(k + 2) * 64 + c];
        float w3 = Wl[(k + 3) * 64 + c];
#pragma unroll
        for (int r = 0; r < 16; r++) {
            float4 a = *(const float4*)(Arow + r * 128 + k);
            acc[r] = fmaf(a.x, w0, fmaf(a.y, w1, fmaf(a.z, w2, fmaf(a.w, w3, acc[r]))));
        }
    }

    if (c < 40) {
        float b = bc[c];
#pragma unroll
        for (int r = 0; r < 16; r++) {
            int gr = row0 + rg * 16 + r;
            if (gr < N) out[(size_t)gr * 40 + c] = acc[r] + b;
        }
    }
}

// ---------- launch ----------
extern "C" void kernel_launch(void* const* d_in, const int* in_sizes, int n_in,
                              void* d_out, int out_size, void* d_ws, size_t ws_size,
                              hipStream_t stream) {
    const float* x  = (const float*)d_in[0];
    const int*   ei = (const int*)d_in[1];
    const float* W1 = (const float*)d_in[2];
    const float* b1 = (const float*)d_in[3];
    const float* W2 = (const float*)d_in[4];
    const float* b2 = (const float*)d_in[5];
    const float* W3 = (const float*)d_in[6];
    const float* b3 = (const float*)d_in[7];
    const float* Wc = (const float*)d_in[8];
    const float* bc = (const float*)d_in[9];

    const int N = in_sizes[0] / 128;   // 50000
    const int E = in_sizes[1] / 2;     // 800000
    const int* src = ei;
    const int* dst = ei + E;

    // workspace carve-out (~30 MB)
    char* ws = (char*)d_ws;
    size_t off = 0;
    auto alloc = [&](size_t bytes) -> void* {
        void* p = ws + off;
        off = (off + bytes + 255) & ~(size_t)255;
        return p;
    };
    float* Mbuf    = (float*)alloc((size_t)N * 128 * 4);
    float* dinv    = (float*)alloc((size_t)N * 4);
    int*   deg     = (int*)alloc((size_t)N * 4);
    int*   row_ptr = (int*)alloc((size_t)(N + 1) * 4);
    int*   cursor  = (int*)alloc((size_t)N * 4);
    int*   csr     = (int*)alloc((size_t)E * 4);
    int*   bsum    = (int*)alloc(256 * 4);

    float* out  = (float*)d_out;               // logits [N,40]
    float* hbuf = out + (size_t)N * 40;        // h region [N,128] — reused as H for all layers

    const int nb = (N + 255) / 256;   // 196 (<=256, required by k_scan2)
    const int eb = (E + 255) / 256;

    k_init_deg<<<nb, 256, 0, stream>>>(deg, N);
    k_count<<<eb, 256, 0, stream>>>(dst, E, deg);
    k_scan1<<<nb, 256, 0, stream>>>(deg, row_ptr, bsum, N);
    k_scan2<<<1, 256, 0, stream>>>(bsum, nb);
    k_scan3<<<nb, 256, 0, stream>>>(deg, row_ptr, bsum, cursor, dinv, N, E);
    k_fill<<<eb, 256, 0, stream>>>(src, dst, E, cursor, csr);

    const int gb  = (N + 63) / 64;    // gemm128 blocks (BM=64)
    const int gab = (N + 3) / 4;      // gather blocks (4 waves/block)

    // layer 1: x -> Mbuf -> hbuf
    k_gemm128<<<gb, 256, 0, stream>>>(x, W1, dinv, Mbuf, N);
    k_gather<<<gab, 256, 0, stream>>>(Mbuf, csr, row_ptr, dinv, b1, hbuf, N);
    // layer 2
    k_gemm128<<<gb, 256, 0, stream>>>(hbuf, W2, dinv, Mbuf, N);
    k_gather<<<gab, 256, 0, stream>>>(Mbuf, csr, row_ptr, dinv, b2, hbuf, N);
    // layer 3: h3 written straight into d_out h-region
    k_gemm128<<<gb, 256, 0, stream>>>(hbuf, W3, dinv, Mbuf, N);
    k_gather<<<gab, 256, 0, stream>>>(Mbuf, csr, row_ptr, dinv, b3, hbuf, N);
    // classifier reads h3 from d_out
    k_gemm40<<<(N + 63) / 64, 256, 0, stream>>>(hbuf, Wc, bc, out, N);
}

// Round 4
// 428.543 us; speedup vs baseline: 1.3178x; 1.1707x over previous
//
#include <hip/hip_runtime.h>

// ---------- helpers ----------
__device__ __forceinline__ float us2f(unsigned short u) {
    union { unsigned int i; float f; } v;
    v.i = ((unsigned int)u) << 16;   // bf16 -> f32 exact
    return v.f;
}
__device__ __forceinline__ unsigned short f2us(float f) {
    union { unsigned int i; float f; } v; v.f = f;
    unsigned int r = v.i + 0x7fff + ((v.i >> 16) & 1);   // round-to-nearest-even
    return (unsigned short)(r >> 16);
}

// ---------- CSR build ----------
__global__ void k_init_deg(int* __restrict__ deg, int N) {
    int i = blockIdx.x * blockDim.x + threadIdx.x;
    if (i < N) deg[i] = 1;            // self-loop
}

__global__ void k_count(const int* __restrict__ dst, int E, int* __restrict__ deg) {
    int e = blockIdx.x * blockDim.x + threadIdx.x;
    if (e < E) atomicAdd(&deg[dst[e]], 1);
}

// block-wise exclusive scan of (deg-1) = in-degree (CSR holds real edges only)
__global__ void k_scan1(const int* __restrict__ deg, int* __restrict__ row_ptr,
                        int* __restrict__ bsum, int N) {
    __shared__ int s[256];
    int t = threadIdx.x;
    int i = blockIdx.x * 256 + t;
    int v = (i < N) ? (deg[i] - 1) : 0;
    s[t] = v; __syncthreads();
    for (int off = 1; off < 256; off <<= 1) {
        int x = (t >= off) ? s[t - off] : 0;
        __syncthreads();
        s[t] += x;
        __syncthreads();
    }
    if (i < N) row_ptr[i] = s[t] - v;          // exclusive within block
    if (t == 255) bsum[blockIdx.x] = s[255];   // block total
}

__global__ void k_scan2(int* __restrict__ bsum, int nb) {  // nb <= 256
    __shared__ int s[256];
    int t = threadIdx.x;
    int v = (t < nb) ? bsum[t] : 0;
    s[t] = v; __syncthreads();
    for (int off = 1; off < 256; off <<= 1) {
        int x = (t >= off) ? s[t - off] : 0;
        __syncthreads();
        s[t] += x;
        __syncthreads();
    }
    if (t < nb) bsum[t] = s[t] - v;            // exclusive
}

__global__ void k_scan3(const int* __restrict__ deg, int* __restrict__ row_ptr,
                        const int* __restrict__ bsum, int* __restrict__ cursor,
                        float* __restrict__ dinv, int N, int E) {
    int i = blockIdx.x * 256 + threadIdx.x;
    if (i < N) {
        int rp = row_ptr[i] + bsum[blockIdx.x];
        row_ptr[i] = rp;
        cursor[i]  = rp;
        dinv[i]    = rsqrtf((float)deg[i]);    // deg >= 1 always
    }
    if (i == 0) row_ptr[N] = E;
}

__global__ void k_fill(const int* __restrict__ src, const int* __restrict__ dst, int E,
                       int* __restrict__ cursor, int* __restrict__ csr) {
    int e = blockIdx.x * blockDim.x + threadIdx.x;
    if (e < E) {
        int p = atomicAdd(&cursor[dst[e]], 1);
        csr[p] = src[e];
    }
}

// ---------- GEMM: M[i][c] = bf16((sum_k A[i][k] * W[k][c]) * dinv[i]) ----------
// Register-tiled: BM=64, BN=128, BK=32 double-buffered. 256 threads, each
// computes a 4x8 micro-tile. A staged transposed [k][row]; W rows staggered
// +4 words per 32 cols (2-way bank aliasing = free).
#define WS_STRIDE 144   // 128 + 4*4 stagger
__global__ __launch_bounds__(256) void k_gemm128(const float* __restrict__ A,
                                                 const float* __restrict__ W,
                                                 const float* __restrict__ dinv,
                                                 unsigned short* __restrict__ M, int N) {
    __shared__ __align__(16) float As[2][32 * 64];        // 16 KB
    __shared__ __align__(16) float Ws[2][32 * WS_STRIDE]; // 36.9 KB
    int t = threadIdx.x;
    int row0 = blockIdx.x * 64;

    // staging indices
    int arow = t & 63;              // A row within tile
    int akk  = (t >> 6) * 8;        // starting k within stage (0,8,16,24)
    bool avalid = (row0 + arow) < N;
    const float* Aptr = A + (size_t)(avalid ? (row0 + arow) : 0) * 128;

    // compute indices
    int rg = t >> 4;                // 0..15 -> rows rg*4..rg*4+3
    int cg = t & 15;                // 0..15 -> cols cg*8..cg*8+7
    int wofs = cg * 8 + ((cg >> 2) << 2);   // staggered col offset

    float4 are0, are1, wre[4];
    const float4* Wp = (const float4*)W;

    auto load_stage = [&](int s) {
        int k0 = s * 32;
        if (avalid) {
            are0 = *(const float4*)(Aptr + k0 + akk);
            are1 = *(const float4*)(Aptr + k0 + akk + 4);
        } else {
            are0 = make_float4(0.f, 0.f, 0.f, 0.f);
            are1 = are0;
        }
#pragma unroll
        for (int i = 0; i < 4; i++) {
            int j = t + i * 256;                 // float4 idx within stage, <1024
            wre[i] = Wp[(size_t)k0 * 32 + j];
        }
    };
    auto store_stage = [&](int b) {
        float* ap = (float*)&are0;
#pragma unroll
        for (int j = 0; j < 4; j++) As[b][(akk + j) * 64 + arow] = ap[j];
        ap = (float*)&are1;
#pragma unroll
        for (int j = 0; j < 4; j++) As[b][(akk + 4 + j) * 64 + arow] = ap[j];
#pragma unroll
        for (int i = 0; i < 4; i++) {
            int j = t + i * 256;
            int k = j >> 5, c4 = (j & 31) * 4;
            *(float4*)&Ws[b][k * WS_STRIDE + c4 + ((c4 >> 5) << 2)] = wre[i];
        }
    };

    float acc[4][8];
#pragma unroll
    for (int i = 0; i < 4; i++)
#pragma unroll
        for (int j = 0; j < 8; j++) acc[i][j] = 0.f;

    load_stage(0);
    store_stage(0);
    __syncthreads();

    for (int s = 0; s < 4; s++) {
        int b = s & 1;
        if (s < 3) load_stage(s + 1);
#pragma unroll 8
        for (int k = 0; k < 32; k++) {
            float4 a  = *(const float4*)&As[b][k * 64 + rg * 4];
            float4 w0 = *(const float4*)&Ws[b][k * WS_STRIDE + wofs];
            float4 w1 = *(const float4*)&Ws[b][k * WS_STRIDE + wofs + 4];
            float av[4] = {a.x, a.y, a.z, a.w};
#pragma unroll
            for (int i = 0; i < 4; i++) {
                acc[i][0] = fmaf(av[i], w0.x, acc[i][0]);
                acc[i][1] = fmaf(av[i], w0.y, acc[i][1]);
                acc[i][2] = fmaf(av[i], w0.z, acc[i][2]);
                acc[i][3] = fmaf(av[i], w0.w, acc[i][3]);
                acc[i][4] = fmaf(av[i], w1.x, acc[i][4]);
                acc[i][5] = fmaf(av[i], w1.y, acc[i][5]);
                acc[i][6] = fmaf(av[i], w1.z, acc[i][6]);
                acc[i][7] = fmaf(av[i], w1.w, acc[i][7]);
            }
        }
        if (s < 3) {
            store_stage((s + 1) & 1);
            __syncthreads();
        }
    }

#pragma unroll
    for (int i = 0; i < 4; i++) {
        int gr = row0 + rg * 4 + i;
        if (gr < N) {
            float dv = dinv[gr];
            union { unsigned short u[8]; uint4 v; } p;
#pragma unroll
            for (int j = 0; j < 8; j++) p.u[j] = f2us(acc[i][j] * dv);
            *(uint4*)&M[(size_t)gr * 128 + cg * 8] = p.v;   // 16 B store
        }
    }
}

// ---------- gather: H[v] = relu(dinv[v]*(m[v] + sum_{u->v} m[u]) + b) ----------
// one wave per node; lane handles features (2*lane, 2*lane+1); bf16 M rows (256 B)
__global__ __launch_bounds__(256) void k_gather(const unsigned short* __restrict__ M,
                                                const int* __restrict__ csr,
                                                const int* __restrict__ row_ptr,
                                                const float* __restrict__ dinv,
                                                const float* __restrict__ bias,
                                                float* __restrict__ H, int N) {
    int w    = (blockIdx.x << 2) + (threadIdx.x >> 6);
    int lane = threadIdx.x & 63;
    if (w >= N) return;

    const ushort2* M2 = (const ushort2*)M;   // row stride 64 ushort2
    float2 acc;
    {
        ushort2 p = M2[(size_t)w * 64 + lane];     // self term
        acc = make_float2(us2f(p.x), us2f(p.y));
    }
    int s0 = row_ptr[w], s1 = row_ptr[w + 1];

    for (int base = s0; base < s1; base += 64) {
        int n = s1 - base; if (n > 64) n = 64;
        int u = (lane < n) ? csr[base + lane] : 0;
        int j = 0;
        for (; j + 4 <= n; j += 4) {
            int u0 = __shfl(u, j), u1 = __shfl(u, j + 1);
            int u2 = __shfl(u, j + 2), u3 = __shfl(u, j + 3);
            ushort2 t0 = M2[(size_t)u0 * 64 + lane];
            ushort2 t1 = M2[(size_t)u1 * 64 + lane];
            ushort2 t2 = M2[(size_t)u2 * 64 + lane];
            ushort2 t3 = M2[(size_t)u3 * 64 + lane];
            acc.x += (us2f(t0.x) + us2f(t1.x)) + (us2f(t2.x) + us2f(t3.x));
            acc.y += (us2f(t0.y) + us2f(t1.y)) + (us2f(t2.y) + us2f(t3.y));
        }
        for (; j < n; j++) {
            int uj = __shfl(u, j);
            ushort2 tj = M2[(size_t)uj * 64 + lane];
            acc.x += us2f(tj.x); acc.y += us2f(tj.y);
        }
    }

    float dv = dinv[w];
    float bx = bias[2 * lane], by = bias[2 * lane + 1];
    float ox = fmaxf(fmaf(dv, acc.x, bx), 0.f);
    float oy = fmaxf(fmaf(dv, acc.y, by), 0.f);
    ((float2*)H)[(size_t)w * 64 + lane] = make_float2(ox, oy);
}

// ---------- classifier: out[i][c] = sum_k h[i][k]*Wc[k][c] + bc[c], c<40 ----------
// block = 256 threads, 64 rows/block, cols padded to 64; thread: 16 rows x 1 col
__global__ __launch_bounds__(256) void k_gemm40(const float* __restrict__ A,
                                                const float* __restrict__ Wc,
                                                const float* __restrict__ bc,
                                                float* __restrict__ out, int N) {
    __shared__ __align__(16) float Wl[128 * 64];  // 32 KB (cols padded 40->64)
    __shared__ __align__(16) float Al[64 * 128];  // 32 KB
    int t = threadIdx.x;

    for (int i = 0; i < 32; i++) Wl[t + i * 256] = 0.f;   // zero padded cols
    __syncthreads();

    {   // Wc is 128x40: elem j=(k*40+c) -> Wl[k*64+c]
        for (int i = 0; i < 20; i++) {
            int j = t + i * 256;                  // < 5120
            int k = j / 40, c = j - 40 * k;
            Wl[k * 64 + c] = Wc[j];
        }
    }

    int row0 = blockIdx.x * 64;
    int tileElems = (N - row0 < 64 ? N - row0 : 64) * 128;
    {
        const float4* Ap = (const float4*)(A + (size_t)row0 * 128);
        for (int i = 0; i < 8; i++) {
            int idx = t + i * 256;                // f4 index (< 2048)
            float4 v;
            if (4 * idx < tileElems) v = Ap[idx];
            else { v.x = v.y = v.z = v.w = 0.f; }
            ((float4*)Al)[idx] = v;
        }
    }
    __syncthreads();

    int c  = t & 63;
    int rg = t >> 6;                              // 0..3 (wave-uniform)
    const float* Arow = Al + rg * 16 * 128;

    float acc[16];
#pragma unroll
    for (int r = 0; r < 16; r++) acc[r] = 0.f;

    for (int k = 0; k < 128; k += 4) {
        float w0 = Wl[(k + 0) * 64 + c];
        float w1 = Wl[(k + 1) * 64 + c];
        float w2 = Wl[(k + 2) * 64 + c];
        float w3 = Wl[(k + 3) * 64 + c];
#pragma unroll
        for (int r = 0; r < 16; r++) {
            float4 a = *(const float4*)(Arow + r * 128 + k);
            acc[r] = fmaf(a.x, w0, fmaf(a.y, w1, fmaf(a.z, w2, fmaf(a.w, w3, acc[r]))));
        }
    }

    if (c < 40) {
        float b = bc[c];
#pragma unroll
        for (int r = 0; r < 16; r++) {
            int gr = row0 + rg * 16 + r;
            if (gr < N) out[(size_t)gr * 40 + c] = acc[r] + b;
        }
    }
}

// ---------- launch ----------
extern "C" void kernel_launch(void* const* d_in, const int* in_sizes, int n_in,
                              void* d_out, int out_size, void* d_ws, size_t ws_size,
                              hipStream_t stream) {
    const float* x  = (const float*)d_in[0];
    const int*   ei = (const int*)d_in[1];
    const float* W1 = (const float*)d_in[2];
    const float* b1 = (const float*)d_in[3];
    const float* W2 = (const float*)d_in[4];
    const float* b2 = (const float*)d_in[5];
    const float* W3 = (const float*)d_in[6];
    const float* b3 = (const float*)d_in[7];
    const float* Wc = (const float*)d_in[8];
    const float* bc = (const float*)d_in[9];

    const int N = in_sizes[0] / 128;   // 50000
    const int E = in_sizes[1] / 2;     // 800000
    const int* src = ei;
    const int* dst = ei + E;

    // workspace carve-out (~17 MB)
    char* ws = (char*)d_ws;
    size_t off = 0;
    auto alloc = [&](size_t bytes) -> void* {
        void* p = ws + off;
        off = (off + bytes + 255) & ~(size_t)255;
        return p;
    };
    unsigned short* Mbuf = (unsigned short*)alloc((size_t)N * 128 * 2);  // bf16
    float* dinv    = (float*)alloc((size_t)N * 4);
    int*   deg     = (int*)alloc((size_t)N * 4);
    int*   row_ptr = (int*)alloc((size_t)(N + 1) * 4);
    int*   cursor  = (int*)alloc((size_t)N * 4);
    int*   csr     = (int*)alloc((size_t)E * 4);
    int*   bsum    = (int*)alloc(256 * 4);

    float* out  = (float*)d_out;               // logits [N,40]
    float* hbuf = out + (size_t)N * 40;        // h region [N,128] — reused as H for all layers

    const int nb = (N + 255) / 256;   // 196 (<=256, required by k_scan2)
    const int eb = (E + 255) / 256;

    k_init_deg<<<nb, 256, 0, stream>>>(deg, N);
    k_count<<<eb, 256, 0, stream>>>(dst, E, deg);
    k_scan1<<<nb, 256, 0, stream>>>(deg, row_ptr, bsum, N);
    k_scan2<<<1, 256, 0, stream>>>(bsum, nb);
    k_scan3<<<nb, 256, 0, stream>>>(deg, row_ptr, bsum, cursor, dinv, N, E);
    k_fill<<<eb, 256, 0, stream>>>(src, dst, E, cursor, csr);

    const int gb  = (N + 63) / 64;    // gemm128 blocks (BM=64)
    const int gab = (N + 3) / 4;      // gather blocks (4 waves/block)

    // layer 1: x -> Mbuf(bf16) -> hbuf
    k_gemm128<<<gb, 256, 0, stream>>>(x, W1, dinv, Mbuf, N);
    k_gather<<<gab, 256, 0, stream>>>(Mbuf, csr, row_ptr, dinv, b1, hbuf, N);
    // layer 2
    k_gemm128<<<gb, 256, 0, stream>>>(hbuf, W2, dinv, Mbuf, N);
    k_gather<<<gab, 256, 0, stream>>>(Mbuf, csr, row_ptr, dinv, b2, hbuf, N);
    // layer 3: h3 written straight into d_out h-region
    k_gemm128<<<gb, 256, 0, stream>>>(hbuf, W3, dinv, Mbuf, N);
    k_gather<<<gab, 256, 0, stream>>>(Mbuf, csr, row_ptr, dinv, b3, hbuf, N);
    // classifier reads h3 from d_out
    k_gemm40<<<(N + 63) / 64, 256, 0, stream>>>(hbuf, Wc, bc, out, N);
}

// Round 5
// 387.370 us; speedup vs baseline: 1.4578x; 1.1063x over previous
//
#include <hip/hip_runtime.h>

// ---------- helpers ----------
__device__ __forceinline__ float us2f(unsigned short u) {
    union { unsigned int i; float f; } v;
    v.i = ((unsigned int)u) << 16;   // bf16 -> f32 exact
    return v.f;
}
__device__ __forceinline__ unsigned short f2us(float f) {
    union { unsigned int i; float f; } v; v.f = f;
    unsigned int r = v.i + 0x7fff + ((v.i >> 16) & 1);   // round-to-nearest-even
    return (unsigned short)(r >> 16);
}

// ================= CSR build: two-level bucket sort =================
// Bucket = dst>>8 (256 nodes per bucket). Edge payload packed as
// (src<<8)|(dst&255) — valid for src < 2^24.

__global__ void k_zero(int* __restrict__ bcnt) {        // 1 WG x 256
    bcnt[threadIdx.x] = 0;
}

// per-WG LDS histogram of dst>>8, merged into global bcnt
__global__ __launch_bounds__(256) void k_hist(const int* __restrict__ dst, int E, int chunk,
                                              int* __restrict__ bcnt) {
    __shared__ int cnt[256];
    int t = threadIdx.x;
    cnt[t] = 0; __syncthreads();
    int s = blockIdx.x * chunk;
    int e = s + chunk; if (e > E) e = E;
    for (int i = s + t; i < e; i += 256) atomicAdd(&cnt[dst[i] >> 8], 1);
    __syncthreads();
    if (cnt[t]) atomicAdd(&bcnt[t], cnt[t]);
}

// exclusive scan of bcnt[256] -> bofs[257], init gcur
__global__ void k_bscan(const int* __restrict__ bcnt, int* __restrict__ bofs,
                        int* __restrict__ gcur) {
    __shared__ int s[256];
    int t = threadIdx.x;
    int v = bcnt[t];
    s[t] = v; __syncthreads();
    for (int off = 1; off < 256; off <<= 1) {
        int x = (t >= off) ? s[t - off] : 0;
        __syncthreads();
        s[t] += x;
        __syncthreads();
    }
    int ex = s[t] - v;
    bofs[t] = ex; gcur[t] = ex;
    if (t == 255) bofs[256] = s[255];
}

// aggregated scatter into buckets: LDS count -> global reserve -> LDS-rank write
__global__ __launch_bounds__(256) void k_scatter1(const int* __restrict__ src,
                                                  const int* __restrict__ dst, int E, int chunk,
                                                  int* __restrict__ gcur,
                                                  unsigned int* __restrict__ pk) {
    __shared__ int cnt[256];
    int t = threadIdx.x;
    cnt[t] = 0; __syncthreads();
    int s = blockIdx.x * chunk;
    int e = s + chunk; if (e > E) e = E;
    for (int i = s + t; i < e; i += 256) atomicAdd(&cnt[dst[i] >> 8], 1);
    __syncthreads();
    int base = atomicAdd(&gcur[t], cnt[t]);   // reserve this WG's chunk of bucket t
    cnt[t] = base;
    __syncthreads();
    for (int i = s + t; i < e; i += 256) {
        int d = dst[i];
        int slot = atomicAdd(&cnt[d >> 8], 1);
        pk[slot] = ((unsigned int)src[i] << 8) | (unsigned int)(d & 255);
    }
}

// per-bucket in-degree histogram -> coalesced indeg write
__global__ __launch_bounds__(256) void k_deg(const unsigned int* __restrict__ pk,
                                             const int* __restrict__ bofs,
                                             int* __restrict__ indeg, int N) {
    __shared__ int cnt[256];
    int t = threadIdx.x, b = blockIdx.x;
    cnt[t] = 0; __syncthreads();
    int s = bofs[b], e = bofs[b + 1];
    for (int i = s + t; i < e; i += 256) atomicAdd(&cnt[pk[i] & 255], 1);
    __syncthreads();
    int node = (b << 8) + t;
    if (node < N) indeg[node] = cnt[t];
}

// block-wise exclusive scan of indeg
__global__ void k_scan1(const int* __restrict__ indeg, int* __restrict__ row_ptr,
                        int* __restrict__ bsum, int N) {
    __shared__ int s[256];
    int t = threadIdx.x;
    int i = blockIdx.x * 256 + t;
    int v = (i < N) ? indeg[i] : 0;
    s[t] = v; __syncthreads();
    for (int off = 1; off < 256; off <<= 1) {
        int x = (t >= off) ? s[t - off] : 0;
        __syncthreads();
        s[t] += x;
        __syncthreads();
    }
    if (i < N) row_ptr[i] = s[t] - v;          // exclusive within block
    if (t == 255) bsum[blockIdx.x] = s[255];   // block total
}

__global__ void k_scan2(int* __restrict__ bsum, int nb) {  // nb <= 256
    __shared__ int s[256];
    int t = threadIdx.x;
    int v = (t < nb) ? bsum[t] : 0;
    s[t] = v; __syncthreads();
    for (int off = 1; off < 256; off <<= 1) {
        int x = (t >= off) ? s[t - off] : 0;
        __syncthreads();
        s[t] += x;
        __syncthreads();
    }
    if (t < nb) bsum[t] = s[t] - v;            // exclusive
}

__global__ void k_scan3(const int* __restrict__ indeg, int* __restrict__ row_ptr,
                        const int* __restrict__ bsum, float* __restrict__ dinv,
                        int N, int E) {
    int i = blockIdx.x * 256 + threadIdx.x;
    if (i < N) {
        row_ptr[i] += bsum[blockIdx.x];
        dinv[i] = rsqrtf((float)(indeg[i] + 1));   // +1 self-loop
    }
    if (i == 0) row_ptr[N] = E;
}

// per-bucket placement: writes land in a ~16KB contiguous csr window
__global__ __launch_bounds__(256) void k_scatter2(const unsigned int* __restrict__ pk,
                                                  const int* __restrict__ bofs,
                                                  const int* __restrict__ row_ptr,
                                                  int* __restrict__ csr, int N) {
    __shared__ int cur[256];
    int t = threadIdx.x, b = blockIdx.x;
    int node = (b << 8) + t;
    cur[t] = (node < N) ? row_ptr[node] : 0;
    __syncthreads();
    int s = bofs[b], e = bofs[b + 1];
    for (int i = s + t; i < e; i += 256) {
        unsigned int v = pk[i];
        int slot = atomicAdd(&cur[v & 255], 1);
        csr[slot] = (int)(v >> 8);
    }
}

// ---------- GEMM: M[i][c] = bf16((sum_k A[i][k] * W[k][c]) * dinv[i]) ----------
// Register-tiled: BM=64, BN=128, BK=32 double-buffered. 256 threads, each
// computes a 4x8 micro-tile. A staged transposed [k][row]; W rows staggered
// +4 words per 32 cols (2-way bank aliasing = free).
#define WS_STRIDE 144   // 128 + 4*4 stagger
__global__ __launch_bounds__(256) void k_gemm128(const float* __restrict__ A,
                                                 const float* __restrict__ W,
                                                 const float* __restrict__ dinv,
                                                 unsigned short* __restrict__ M, int N) {
    __shared__ __align__(16) float As[2][32 * 64];        // 16 KB
    __shared__ __align__(16) float Ws[2][32 * WS_STRIDE]; // 36.9 KB
    int t = threadIdx.x;
    int row0 = blockIdx.x * 64;

    // staging indices
    int arow = t & 63;              // A row within tile
    int akk  = (t >> 6) * 8;        // starting k within stage (0,8,16,24)
    bool avalid = (row0 + arow) < N;
    const float* Aptr = A + (size_t)(avalid ? (row0 + arow) : 0) * 128;

    // compute indices
    int rg = t >> 4;                // 0..15 -> rows rg*4..rg*4+3
    int cg = t & 15;                // 0..15 -> cols cg*8..cg*8+7
    int wofs = cg * 8 + ((cg >> 2) << 2);   // staggered col offset

    float4 are0, are1, wre[4];
    const float4* Wp = (const float4*)W;

    auto load_stage = [&](int s) {
        int k0 = s * 32;
        if (avalid) {
            are0 = *(const float4*)(Aptr + k0 + akk);
            are1 = *(const float4*)(Aptr + k0 + akk + 4);
        } else {
            are0 = make_float4(0.f, 0.f, 0.f, 0.f);
            are1 = are0;
        }
#pragma unroll
        for (int i = 0; i < 4; i++) {
            int j = t + i * 256;                 // float4 idx within stage, <1024
            wre[i] = Wp[(size_t)k0 * 32 + j];
        }
    };
    auto store_stage = [&](int b) {
        float* ap = (float*)&are0;
#pragma unroll
        for (int j = 0; j < 4; j++) As[b][(akk + j) * 64 + arow] = ap[j];
        ap = (float*)&are1;
#pragma unroll
        for (int j = 0; j < 4; j++) As[b][(akk + 4 + j) * 64 + arow] = ap[j];
#pragma unroll
        for (int i = 0; i < 4; i++) {
            int j = t + i * 256;
            int k = j >> 5, c4 = (j & 31) * 4;
            *(float4*)&Ws[b][k * WS_STRIDE + c4 + ((c4 >> 5) << 2)] = wre[i];
        }
    };

    float acc[4][8];
#pragma unroll
    for (int i = 0; i < 4; i++)
#pragma unroll
        for (int j = 0; j < 8; j++) acc[i][j] = 0.f;

    load_stage(0);
    store_stage(0);
    __syncthreads();

    for (int s = 0; s < 4; s++) {
        int b = s & 1;
        if (s < 3) load_stage(s + 1);
#pragma unroll 8
        for (int k = 0; k < 32; k++) {
            float4 a  = *(const float4*)&As[b][k * 64 + rg * 4];
            float4 w0 = *(const float4*)&Ws[b][k * WS_STRIDE + wofs];
            float4 w1 = *(const float4*)&Ws[b][k * WS_STRIDE + wofs + 4];
            float av[4] = {a.x, a.y, a.z, a.w};
#pragma unroll
            for (int i = 0; i < 4; i++) {
                acc[i][0] = fmaf(av[i], w0.x, acc[i][0]);
                acc[i][1] = fmaf(av[i], w0.y, acc[i][1]);
                acc[i][2] = fmaf(av[i], w0.z, acc[i][2]);
                acc[i][3] = fmaf(av[i], w0.w, acc[i][3]);
                acc[i][4] = fmaf(av[i], w1.x, acc[i][4]);
                acc[i][5] = fmaf(av[i], w1.y, acc[i][5]);
                acc[i][6] = fmaf(av[i], w1.z, acc[i][6]);
                acc[i][7] = fmaf(av[i], w1.w, acc[i][7]);
            }
        }
        if (s < 3) {
            store_stage((s + 1) & 1);
            __syncthreads();
        }
    }

#pragma unroll
    for (int i = 0; i < 4; i++) {
        int gr = row0 + rg * 4 + i;
        if (gr < N) {
            float dv = dinv[gr];
            union { unsigned short u[8]; uint4 v; } p;
#pragma unroll
            for (int j = 0; j < 8; j++) p.u[j] = f2us(acc[i][j] * dv);
            *(uint4*)&M[(size_t)gr * 128 + cg * 8] = p.v;   // 16 B store
        }
    }
}

// ---------- gather: H[v] = relu(dinv[v]*(m[v] + sum_{u->v} m[u]) + b) ----------
// one wave per node; lane handles features (2*lane, 2*lane+1); bf16 M rows (256 B)
__global__ __launch_bounds__(256) void k_gather(const unsigned short* __restrict__ M,
                                                const int* __restrict__ csr,
                                                const int* __restrict__ row_ptr,
                                                const float* __restrict__ dinv,
                                                const float* __restrict__ bias,
                                                float* __restrict__ H, int N) {
    int w    = (blockIdx.x << 2) + (threadIdx.x >> 6);
    int lane = threadIdx.x & 63;
    if (w >= N) return;

    const ushort2* M2 = (const ushort2*)M;   // row stride 64 ushort2
    float2 acc;
    {
        ushort2 p = M2[(size_t)w * 64 + lane];     // self term
        acc = make_float2(us2f(p.x), us2f(p.y));
    }
    int s0 = row_ptr[w], s1 = row_ptr[w + 1];

    for (int base = s0; base < s1; base += 64) {
        int n = s1 - base; if (n > 64) n = 64;
        int u = (lane < n) ? csr[base + lane] : 0;
        int j = 0;
        for (; j + 4 <= n; j += 4) {
            int u0 = __shfl(u, j), u1 = __shfl(u, j + 1);
            int u2 = __shfl(u, j + 2), u3 = __shfl(u, j + 3);
            ushort2 t0 = M2[(size_t)u0 * 64 + lane];
            ushort2 t1 = M2[(size_t)u1 * 64 + lane];
            ushort2 t2 = M2[(size_t)u2 * 64 + lane];
            ushort2 t3 = M2[(size_t)u3 * 64 + lane];
            acc.x += (us2f(t0.x) + us2f(t1.x)) + (us2f(t2.x) + us2f(t3.x));
            acc.y += (us2f(t0.y) + us2f(t1.y)) + (us2f(t2.y) + us2f(t3.y));
        }
        for (; j < n; j++) {
            int uj = __shfl(u, j);
            ushort2 tj = M2[(size_t)uj * 64 + lane];
            acc.x += us2f(tj.x); acc.y += us2f(tj.y);
        }
    }

    float dv = dinv[w];
    float bx = bias[2 * lane], by = bias[2 * lane + 1];
    float ox = fmaxf(fmaf(dv, acc.x, bx), 0.f);
    float oy = fmaxf(fmaf(dv, acc.y, by), 0.f);
    ((float2*)H)[(size_t)w * 64 + lane] = make_float2(ox, oy);
}

// ---------- classifier: out[i][c] = sum_k h[i][k]*Wc[k][c] + bc[c], c<40 ----------
// block = 256 threads, 64 rows/block, cols padded to 64; thread: 16 rows x 1 col
__global__ __launch_bounds__(256) void k_gemm40(const float* __restrict__ A,
                                                const float* __restrict__ Wc,
                                                const float* __restrict__ bc,
                                                float* __restrict__ out, int N) {
    __shared__ __align__(16) float Wl[128 * 64];  // 32 KB (cols padded 40->64)
    __shared__ __align__(16) float Al[64 * 128];  // 32 KB
    int t = threadIdx.x;

    for (int i = 0; i < 32; i++) Wl[t + i * 256] = 0.f;   // zero padded cols
    __syncthreads();

    {   // Wc is 128x40: elem j=(k*40+c) -> Wl[k*64+c]
        for (int i = 0; i < 20; i++) {
            int j = t + i * 256;                  // < 5120
            int k = j / 40, c = j - 40 * k;
            Wl[k * 64 + c] = Wc[j];
        }
    }

    int row0 = blockIdx.x * 64;
    int tileElems = (N - row0 < 64 ? N - row0 : 64) * 128;
    {
        const float4* Ap = (const float4*)(A + (size_t)row0 * 128);
        for (int i = 0; i < 8; i++) {
            int idx = t + i * 256;                // f4 index (< 2048)
            float4 v;
            if (4 * idx < tileElems) v = Ap[idx];
            else { v.x = v.y = v.z = v.w = 0.f; }
            ((float4*)Al)[idx] = v;
        }
    }
    __syncthreads();

    int c  = t & 63;
    int rg = t >> 6;                              // 0..3 (wave-uniform)
    const float* Arow = Al + rg * 16 * 128;

    float acc[16];
#pragma unroll
    for (int r = 0; r < 16; r++) acc[r] = 0.f;

    for (int k = 0; k < 128; k += 4) {
        float w0 = Wl[(k + 0) * 64 + c];
        float w1 = Wl[(k + 1) * 64 + c];
        float w2 = Wl[(k + 2) * 64 + c];
        float w3 = Wl[(k + 3) * 64 + c];
#pragma unroll
        for (int r = 0; r < 16; r++) {
            float4 a = *(const float4*)(Arow + r * 128 + k);
            acc[r] = fmaf(a.x, w0, fmaf(a.y, w1, fmaf(a.z, w2, fmaf(a.w, w3, acc[r]))));
        }
    }

    if (c < 40) {
        float b = bc[c];
#pragma unroll
        for (int r = 0; r < 16; r++) {
            int gr = row0 + rg * 16 + r;
            if (gr < N) out[(size_t)gr * 40 + c] = acc[r] + b;
        }
    }
}

// ---------- launch ----------
extern "C" void kernel_launch(void* const* d_in, const int* in_sizes, int n_in,
                              void* d_out, int out_size, void* d_ws, size_t ws_size,
                              hipStream_t stream) {
    const float* x  = (const float*)d_in[0];
    const int*   ei = (const int*)d_in[1];
    const float* W1 = (const float*)d_in[2];
    const float* b1 = (const float*)d_in[3];
    const float* W2 = (const float*)d_in[4];
    const float* b2 = (const float*)d_in[5];
    const float* W3 = (const float*)d_in[6];
    const float* b3 = (const float*)d_in[7];
    const float* Wc = (const float*)d_in[8];
    const float* bc = (const float*)d_in[9];

    const int N = in_sizes[0] / 128;   // 50000
    const int E = in_sizes[1] / 2;     // 800000
    const int* src = ei;
    const int* dst = ei + E;

    // workspace carve-out (~24 MB)
    char* ws = (char*)d_ws;
    size_t off = 0;
    auto alloc = [&](size_t bytes) -> void* {
        void* p = ws + off;
        off = (off + bytes + 255) & ~(size_t)255;
        return p;
    };
    unsigned short* Mbuf = (unsigned short*)alloc((size_t)N * 128 * 2);  // bf16
    unsigned int* pk     = (unsigned int*)alloc((size_t)E * 4);          // bucketed edges
    float* dinv    = (float*)alloc((size_t)N * 4);
    int*   indeg   = (int*)alloc((size_t)N * 4);
    int*   row_ptr = (int*)alloc((size_t)(N + 1) * 4);
    int*   csr     = (int*)alloc((size_t)E * 4);
    int*   bcnt    = (int*)alloc(256 * 4);
    int*   bofs    = (int*)alloc(257 * 4);
    int*   gcur    = (int*)alloc(256 * 4);
    int*   bsum    = (int*)alloc(256 * 4);

    float* out  = (float*)d_out;               // logits [N,40]
    float* hbuf = out + (size_t)N * 40;        // h region [N,128] — reused as H for all layers

    const int nb  = (N + 255) / 256;   // 196 (<=256, required by k_scan2)
    const int NB  = (N + 255) >> 8;    // node buckets (196)
    const int G1  = 256;               // hist/scatter1 WGs
    const int chunk = (E + G1 - 1) / G1;

    // CSR build: bucket sort (dst>>8) -> per-bucket degree + placement
    k_zero<<<1, 256, 0, stream>>>(bcnt);
    k_hist<<<G1, 256, 0, stream>>>(dst, E, chunk, bcnt);
    k_bscan<<<1, 256, 0, stream>>>(bcnt, bofs, gcur);
    k_scatter1<<<G1, 256, 0, stream>>>(src, dst, E, chunk, gcur, pk);
    k_deg<<<NB, 256, 0, stream>>>(pk, bofs, indeg, N);
    k_scan1<<<nb, 256, 0, stream>>>(indeg, row_ptr, bsum, N);
    k_scan2<<<1, 256, 0, stream>>>(bsum, nb);
    k_scan3<<<nb, 256, 0, stream>>>(indeg, row_ptr, bsum, dinv, N, E);
    k_scatter2<<<NB, 256, 0, stream>>>(pk, bofs, row_ptr, csr, N);

    const int gb  = (N + 63) / 64;    // gemm128 blocks (BM=64)
    const int gab = (N + 3) / 4;      // gather blocks (4 waves/block)

    // layer 1: x -> Mbuf(bf16) -> hbuf
    k_gemm128<<<gb, 256, 0, stream>>>(x, W1, dinv, Mbuf, N);
    k_gather<<<gab, 256, 0, stream>>>(Mbuf, csr, row_ptr, dinv, b1, hbuf, N);
    // layer 2
    k_gemm128<<<gb, 256, 0, stream>>>(hbuf, W2, dinv, Mbuf, N);
    k_gather<<<gab, 256, 0, stream>>>(Mbuf, csr, row_ptr, dinv, b2, hbuf, N);
    // layer 3: h3 written straight into d_out h-region
    k_gemm128<<<gb, 256, 0, stream>>>(hbuf, W3, dinv, Mbuf, N);
    k_gather<<<gab, 256, 0, stream>>>(Mbuf, csr, row_ptr, dinv, b3, hbuf, N);
    // classifier reads h3 from d_out
    k_gemm40<<<(N + 63) / 64, 256, 0, stream>>>(hbuf, Wc, bc, out, N);
}

// Round 6
// 326.744 us; speedup vs baseline: 1.7283x; 1.1855x over previous
//
#include <hip/hip_runtime.h>

typedef float f32x4 __attribute__((ext_vector_type(4)));
typedef short s16x8 __attribute__((ext_vector_type(8)));

// ---------- helpers ----------
__device__ __forceinline__ float us2f(unsigned short u) {
    union { unsigned int i; float f; } v;
    v.i = ((unsigned int)u) << 16;   // bf16 -> f32 exact
    return v.f;
}
__device__ __forceinline__ unsigned short f2us(float f) {
    union { unsigned int i; float f; } v; v.f = f;
    unsigned int r = v.i + 0x7fff + ((v.i >> 16) & 1);   // round-to-nearest-even
    return (unsigned short)(r >> 16);
}

// ================= CSR build: two-level bucket sort =================
__global__ void k_zero(int* __restrict__ bcnt) {        // 1 WG x 256
    bcnt[threadIdx.x] = 0;
}

__global__ __launch_bounds__(256) void k_hist(const int* __restrict__ dst, int E, int chunk,
                                              int* __restrict__ bcnt) {
    __shared__ int cnt[256];
    int t = threadIdx.x;
    cnt[t] = 0; __syncthreads();
    int s = blockIdx.x * chunk;
    int e = s + chunk; if (e > E) e = E;
    for (int i = s + t; i < e; i += 256) atomicAdd(&cnt[dst[i] >> 8], 1);
    __syncthreads();
    if (cnt[t]) atomicAdd(&bcnt[t], cnt[t]);
}

__global__ void k_bscan(const int* __restrict__ bcnt, int* __restrict__ bofs,
                        int* __restrict__ gcur) {
    __shared__ int s[256];
    int t = threadIdx.x;
    int v = bcnt[t];
    s[t] = v; __syncthreads();
    for (int off = 1; off < 256; off <<= 1) {
        int x = (t >= off) ? s[t - off] : 0;
        __syncthreads();
        s[t] += x;
        __syncthreads();
    }
    int ex = s[t] - v;
    bofs[t] = ex; gcur[t] = ex;
    if (t == 255) bofs[256] = s[255];
}

__global__ __launch_bounds__(256) void k_scatter1(const int* __restrict__ src,
                                                  const int* __restrict__ dst, int E, int chunk,
                                                  int* __restrict__ gcur,
                                                  unsigned int* __restrict__ pk) {
    __shared__ int cnt[256];
    int t = threadIdx.x;
    cnt[t] = 0; __syncthreads();
    int s = blockIdx.x * chunk;
    int e = s + chunk; if (e > E) e = E;
    for (int i = s + t; i < e; i += 256) atomicAdd(&cnt[dst[i] >> 8], 1);
    __syncthreads();
    int base = atomicAdd(&gcur[t], cnt[t]);
    cnt[t] = base;
    __syncthreads();
    for (int i = s + t; i < e; i += 256) {
        int d = dst[i];
        int slot = atomicAdd(&cnt[d >> 8], 1);
        pk[slot] = ((unsigned int)src[i] << 8) | (unsigned int)(d & 255);
    }
}

__global__ __launch_bounds__(256) void k_deg(const unsigned int* __restrict__ pk,
                                             const int* __restrict__ bofs,
                                             int* __restrict__ indeg, int N) {
    __shared__ int cnt[256];
    int t = threadIdx.x, b = blockIdx.x;
    cnt[t] = 0; __syncthreads();
    int s = bofs[b], e = bofs[b + 1];
    for (int i = s + t; i < e; i += 256) atomicAdd(&cnt[pk[i] & 255], 1);
    __syncthreads();
    int node = (b << 8) + t;
    if (node < N) indeg[node] = cnt[t];
}

__global__ void k_scan1(const int* __restrict__ indeg, int* __restrict__ row_ptr,
                        int* __restrict__ bsum, int N) {
    __shared__ int s[256];
    int t = threadIdx.x;
    int i = blockIdx.x * 256 + t;
    int v = (i < N) ? indeg[i] : 0;
    s[t] = v; __syncthreads();
    for (int off = 1; off < 256; off <<= 1) {
        int x = (t >= off) ? s[t - off] : 0;
        __syncthreads();
        s[t] += x;
        __syncthreads();
    }
    if (i < N) row_ptr[i] = s[t] - v;
    if (t == 255) bsum[blockIdx.x] = s[255];
}

__global__ void k_scan2(int* __restrict__ bsum, int nb) {  // nb <= 256
    __shared__ int s[256];
    int t = threadIdx.x;
    int v = (t < nb) ? bsum[t] : 0;
    s[t] = v; __syncthreads();
    for (int off = 1; off < 256; off <<= 1) {
        int x = (t >= off) ? s[t - off] : 0;
        __syncthreads();
        s[t] += x;
        __syncthreads();
    }
    if (t < nb) bsum[t] = s[t] - v;
}

__global__ void k_scan3(const int* __restrict__ indeg, int* __restrict__ row_ptr,
                        const int* __restrict__ bsum, float* __restrict__ dinv,
                        int N, int E) {
    int i = blockIdx.x * 256 + threadIdx.x;
    if (i < N) {
        row_ptr[i] += bsum[blockIdx.x];
        dinv[i] = rsqrtf((float)(indeg[i] + 1));   // +1 self-loop
    }
    if (i == 0) row_ptr[N] = E;
}

__global__ __launch_bounds__(256) void k_scatter2(const unsigned int* __restrict__ pk,
                                                  const int* __restrict__ bofs,
                                                  const int* __restrict__ row_ptr,
                                                  int* __restrict__ csr, int N) {
    __shared__ int cur[256];
    int t = threadIdx.x, b = blockIdx.x;
    int node = (b << 8) + t;
    cur[t] = (node < N) ? row_ptr[node] : 0;
    __syncthreads();
    int s = bofs[b], e = bofs[b + 1];
    for (int i = s + t; i < e; i += 256) {
        unsigned int v = pk[i];
        int slot = atomicAdd(&cur[v & 255], 1);
        csr[slot] = (int)(v >> 8);
    }
}

// ================= W prep: split fp32 weights into bf16 hi/lo images =================
// Image layout per weight (ushort units): idx(n,k) = n*128 + (((k>>3)^(n&15))<<3) + (k&7)
// XOR k-block swizzle -> conflict-free wave64 b128 fragment reads from LDS.
// img: [L0: H 16384, L 16384][L1][L2][Wc: H 6144, L 6144] (n padded 40->48, zeros)
__global__ void k_wprep(const float* __restrict__ W1, const float* __restrict__ W2,
                        const float* __restrict__ W3, const float* __restrict__ Wc,
                        unsigned short* __restrict__ img) {
    int b = blockIdx.x, n = threadIdx.x;
    if (b < 3) {
        const float* W = (b == 0) ? W1 : ((b == 1) ? W2 : W3);
        unsigned short* H = img + b * 32768;
        unsigned short* L = H + 16384;
        for (int k = 0; k < 128; k++) {
            float f = W[k * 128 + n];
            unsigned short h = f2us(f);
            unsigned short l = f2us(f - us2f(h));
            int idx = n * 128 + ((((k >> 3) ^ (n & 15))) << 3) + (k & 7);
            H[idx] = h; L[idx] = l;
        }
    } else {
        if (n >= 48) return;
        unsigned short* H = img + 3 * 32768;
        unsigned short* L = H + 6144;
        for (int k = 0; k < 128; k++) {
            float f = (n < 40) ? Wc[k * 40 + n] : 0.f;
            unsigned short h = f2us(f);
            unsigned short l = f2us(f - us2f(h));
            int idx = n * 128 + ((((k >> 3) ^ (n & 15))) << 3) + (k & 7);
            H[idx] = h; L[idx] = l;
        }
    }
}

// ================= MFMA GEMM: M[i][c] = bf16((A@W)[i][c] * dinv[i]) =================
// fp32 accuracy via bf16 hi/lo split: A@W = AhWh + AhWl + AlWh (err ~2^-16).
// Block = 64 rows, 4 waves x 16 rows. W image resident in LDS (64 KB, no k-loop
// barriers); A-frags straight from global with in-register hi/lo conversion.
// mfma_f32_16x16x32_bf16: A[m=lane&15][k=quad*8+j]; B-frag = Wt[n][k] 8-contig-k;
// C/D: col=lane&15, row=quad*4+reg  (verified layouts).
__global__ __launch_bounds__(256) void k_gemm128m(const float* __restrict__ A,
                                                  const unsigned short* __restrict__ img,
                                                  const float* __restrict__ dinv,
                                                  unsigned short* __restrict__ M, int N) {
    __shared__ __align__(16) unsigned short WsH[16384];   // 32 KB
    __shared__ __align__(16) unsigned short WsL[16384];   // 32 KB
    int t = threadIdx.x;
    {
        const uint4* s = (const uint4*)img;
        uint4* dH = (uint4*)WsH; uint4* dL = (uint4*)WsL;
#pragma unroll
        for (int i = 0; i < 8; i++) dH[t + i * 256] = s[t + i * 256];
#pragma unroll
        for (int i = 0; i < 8; i++) dL[t + i * 256] = s[2048 + t + i * 256];
    }
    __syncthreads();

    int w = t >> 6, lane = t & 63;
    int m = lane & 15, q = lane >> 4;
    int row0 = blockIdx.x * 64 + w * 16;
    int gr = row0 + m;
    int grc = (gr < N) ? gr : (N - 1);
    const float4* Arow = (const float4*)(A + (size_t)grc * 128);
    int nbase = m * 128;

    f32x4 acc[8];
#pragma unroll
    for (int cb = 0; cb < 8; cb++) { acc[cb][0]=0.f; acc[cb][1]=0.f; acc[cb][2]=0.f; acc[cb][3]=0.f; }

#pragma unroll
    for (int ks = 0; ks < 4; ks++) {
        float4 f0 = Arow[ks * 8 + q * 2];
        float4 f1 = Arow[ks * 8 + q * 2 + 1];
        float fv[8] = {f0.x, f0.y, f0.z, f0.w, f1.x, f1.y, f1.z, f1.w};
        union { unsigned short u[8]; s16x8 v; } ah, al;
#pragma unroll
        for (int j = 0; j < 8; j++) {
            unsigned short h = f2us(fv[j]);
            ah.u[j] = h;
            al.u[j] = f2us(fv[j] - us2f(h));
        }
        int koff = (((ks * 4 + q) ^ m) & 15) << 3;
#pragma unroll
        for (int cb = 0; cb < 8; cb++) {
            int o = cb * 2048 + nbase + koff;
            s16x8 wh = *(const s16x8*)&WsH[o];
            s16x8 wl = *(const s16x8*)&WsL[o];
            acc[cb] = __builtin_amdgcn_mfma_f32_16x16x32_bf16(ah.v, wh, acc[cb], 0, 0, 0);
            acc[cb] = __builtin_amdgcn_mfma_f32_16x16x32_bf16(ah.v, wl, acc[cb], 0, 0, 0);
            acc[cb] = __builtin_amdgcn_mfma_f32_16x16x32_bf16(al.v, wh, acc[cb], 0, 0, 0);
        }
    }

#pragma unroll
    for (int r = 0; r < 4; r++) {
        int grow = row0 + q * 4 + r;
        if (grow < N) {
            float dv = dinv[grow];
#pragma unroll
            for (int cb = 0; cb < 8; cb++)
                M[(size_t)grow * 128 + cb * 16 + m] = f2us(acc[cb][r] * dv);
        }
    }
}

// ================= MFMA classifier: out = h3 @ Wc + bc (cols padded to 48) =========
__global__ __launch_bounds__(256) void k_gemm40m(const float* __restrict__ A,
                                                 const unsigned short* __restrict__ img,
                                                 const float* __restrict__ bc,
                                                 float* __restrict__ out, int N) {
    __shared__ __align__(16) unsigned short WsH[6144];    // 12 KB
    __shared__ __align__(16) unsigned short WsL[6144];    // 12 KB
    int t = threadIdx.x;
    {
        const uint4* s = (const uint4*)img;
        uint4* dH = (uint4*)WsH; uint4* dL = (uint4*)WsL;
#pragma unroll
        for (int i = 0; i < 3; i++) dH[t + i * 256] = s[t + i * 256];
#pragma unroll
        for (int i = 0; i < 3; i++) dL[t + i * 256] = s[768 + t + i * 256];
    }
    __syncthreads();

    int w = t >> 6, lane = t & 63;
    int m = lane & 15, q = lane >> 4;
    int row0 = blockIdx.x * 64 + w * 16;
    int gr = row0 + m;
    int grc = (gr < N) ? gr : (N - 1);
    const float4* Arow = (const float4*)(A + (size_t)grc * 128);
    int nbase = m * 128;

    f32x4 acc[3];
#pragma unroll
    for (int cb = 0; cb < 3; cb++) { acc[cb][0]=0.f; acc[cb][1]=0.f; acc[cb][2]=0.f; acc[cb][3]=0.f; }

#pragma unroll
    for (int ks = 0; ks < 4; ks++) {
        float4 f0 = Arow[ks * 8 + q * 2];
        float4 f1 = Arow[ks * 8 + q * 2 + 1];
        float fv[8] = {f0.x, f0.y, f0.z, f0.w, f1.x, f1.y, f1.z, f1.w};
        union { unsigned short u[8]; s16x8 v; } ah, al;
#pragma unroll
        for (int j = 0; j < 8; j++) {
            unsigned short h = f2us(fv[j]);
            ah.u[j] = h;
            al.u[j] = f2us(fv[j] - us2f(h));
        }
        int koff = (((ks * 4 + q) ^ m) & 15) << 3;
#pragma unroll
        for (int cb = 0; cb < 3; cb++) {
            int o = cb * 2048 + nbase + koff;
            s16x8 wh = *(const s16x8*)&WsH[o];
            s16x8 wl = *(const s16x8*)&WsL[o];
            acc[cb] = __builtin_amdgcn_mfma_f32_16x16x32_bf16(ah.v, wh, acc[cb], 0, 0, 0);
            acc[cb] = __builtin_amdgcn_mfma_f32_16x16x32_bf16(ah.v, wl, acc[cb], 0, 0, 0);
            acc[cb] = __builtin_amdgcn_mfma_f32_16x16x32_bf16(al.v, wh, acc[cb], 0, 0, 0);
        }
    }

#pragma unroll
    for (int r = 0; r < 4; r++) {
        int grow = row0 + q * 4 + r;
        if (grow < N) {
#pragma unroll
            for (int cb = 0; cb < 3; cb++) {
                int col = cb * 16 + m;
                if (col < 40) out[(size_t)grow * 40 + col] = acc[cb][r] + bc[col];
            }
        }
    }
}

// ---------- gather: H[v] = relu(dinv[v]*(m[v] + sum_{u->v} m[u]) + b) ----------
__global__ __launch_bounds__(256) void k_gather(const unsigned short* __restrict__ M,
                                                const int* __restrict__ csr,
                                                const int* __restrict__ row_ptr,
                                                const float* __restrict__ dinv,
                                                const float* __restrict__ bias,
                                                float* __restrict__ H, int N) {
    int w    = (blockIdx.x << 2) + (threadIdx.x >> 6);
    int lane = threadIdx.x & 63;
    if (w >= N) return;

    const ushort2* M2 = (const ushort2*)M;   // row stride 64 ushort2
    float2 acc;
    {
        ushort2 p = M2[(size_t)w * 64 + lane];     // self term
        acc = make_float2(us2f(p.x), us2f(p.y));
    }
    int s0 = row_ptr[w], s1 = row_ptr[w + 1];

    for (int base = s0; base < s1; base += 64) {
        int n = s1 - base; if (n > 64) n = 64;
        int u = (lane < n) ? csr[base + lane] : 0;
        int j = 0;
        for (; j + 4 <= n; j += 4) {
            int u0 = __shfl(u, j), u1 = __shfl(u, j + 1);
            int u2 = __shfl(u, j + 2), u3 = __shfl(u, j + 3);
            ushort2 t0 = M2[(size_t)u0 * 64 + lane];
            ushort2 t1 = M2[(size_t)u1 * 64 + lane];
            ushort2 t2 = M2[(size_t)u2 * 64 + lane];
            ushort2 t3 = M2[(size_t)u3 * 64 + lane];
            acc.x += (us2f(t0.x) + us2f(t1.x)) + (us2f(t2.x) + us2f(t3.x));
            acc.y += (us2f(t0.y) + us2f(t1.y)) + (us2f(t2.y) + us2f(t3.y));
        }
        for (; j < n; j++) {
            int uj = __shfl(u, j);
            ushort2 tj = M2[(size_t)uj * 64 + lane];
            acc.x += us2f(tj.x); acc.y += us2f(tj.y);
        }
    }

    float dv = dinv[w];
    float bx = bias[2 * lane], by = bias[2 * lane + 1];
    float ox = fmaxf(fmaf(dv, acc.x, bx), 0.f);
    float oy = fmaxf(fmaf(dv, acc.y, by), 0.f);
    ((float2*)H)[(size_t)w * 64 + lane] = make_float2(ox, oy);
}

// ---------- launch ----------
extern "C" void kernel_launch(void* const* d_in, const int* in_sizes, int n_in,
                              void* d_out, int out_size, void* d_ws, size_t ws_size,
                              hipStream_t stream) {
    const float* x  = (const float*)d_in[0];
    const int*   ei = (const int*)d_in[1];
    const float* W1 = (const float*)d_in[2];
    const float* b1 = (const float*)d_in[3];
    const float* W2 = (const float*)d_in[4];
    const float* b2 = (const float*)d_in[5];
    const float* W3 = (const float*)d_in[6];
    const float* b3 = (const float*)d_in[7];
    const float* Wc = (const float*)d_in[8];
    const float* bc = (const float*)d_in[9];

    const int N = in_sizes[0] / 128;   // 50000
    const int E = in_sizes[1] / 2;     // 800000
    const int* src = ei;
    const int* dst = ei + E;

    // workspace carve-out (~24.3 MB)
    char* ws = (char*)d_ws;
    size_t off = 0;
    auto alloc = [&](size_t bytes) -> void* {
        void* p = ws + off;
        off = (off + bytes + 255) & ~(size_t)255;
        return p;
    };
    unsigned short* Mbuf = (unsigned short*)alloc((size_t)N * 128 * 2);  // bf16
    unsigned int* pk     = (unsigned int*)alloc((size_t)E * 4);          // bucketed edges
    unsigned short* img  = (unsigned short*)alloc((3 * 32768 + 2 * 6144) * 2);
    float* dinv    = (float*)alloc((size_t)N * 4);
    int*   indeg   = (int*)alloc((size_t)N * 4);
    int*   row_ptr = (int*)alloc((size_t)(N + 1) * 4);
    int*   csr     = (int*)alloc((size_t)E * 4);
    int*   bcnt    = (int*)alloc(256 * 4);
    int*   bofs    = (int*)alloc(257 * 4);
    int*   gcur    = (int*)alloc(256 * 4);
    int*   bsum    = (int*)alloc(256 * 4);

    float* out  = (float*)d_out;               // logits [N,40]
    float* hbuf = out + (size_t)N * 40;        // h region [N,128] — reused for all layers

    const int nb  = (N + 255) / 256;   // 196 (<=256, required by k_scan2)
    const int NB  = (N + 255) >> 8;    // node buckets (196)
    const int G1  = 256;
    const int chunk = (E + G1 - 1) / G1;

    // weight prep (bf16 hi/lo swizzled images)
    k_wprep<<<4, 128, 0, stream>>>(W1, W2, W3, Wc, img);

    // CSR build: bucket sort (dst>>8) -> per-bucket degree + placement
    k_zero<<<1, 256, 0, stream>>>(bcnt);
    k_hist<<<G1, 256, 0, stream>>>(dst, E, chunk, bcnt);
    k_bscan<<<1, 256, 0, stream>>>(bcnt, bofs, gcur);
    k_scatter1<<<G1, 256, 0, stream>>>(src, dst, E, chunk, gcur, pk);
    k_deg<<<NB, 256, 0, stream>>>(pk, bofs, indeg, N);
    k_scan1<<<nb, 256, 0, stream>>>(indeg, row_ptr, bsum, N);
    k_scan2<<<1, 256, 0, stream>>>(bsum, nb);
    k_scan3<<<nb, 256, 0, stream>>>(indeg, row_ptr, bsum, dinv, N, E);
    k_scatter2<<<NB, 256, 0, stream>>>(pk, bofs, row_ptr, csr, N);

    const int gb  = (N + 63) / 64;    // gemm blocks (BM=64)
    const int gab = (N + 3) / 4;      // gather blocks (4 waves/block)

    // layer 1: x -> Mbuf(bf16) -> hbuf
    k_gemm128m<<<gb, 256, 0, stream>>>(x, img, dinv, Mbuf, N);
    k_gather<<<gab, 256, 0, stream>>>(Mbuf, csr, row_ptr, dinv, b1, hbuf, N);
    // layer 2
    k_gemm128m<<<gb, 256, 0, stream>>>(hbuf, img + 32768, dinv, Mbuf, N);
    k_gather<<<gab, 256, 0, stream>>>(Mbuf, csr, row_ptr, dinv, b2, hbuf, N);
    // layer 3: h3 -> d_out h-region
    k_gemm128m<<<gb, 256, 0, stream>>>(hbuf, img + 2 * 32768, dinv, Mbuf, N);
    k_gather<<<gab, 256, 0, stream>>>(Mbuf, csr, row_ptr, dinv, b3, hbuf, N);
    // classifier
    k_gemm40m<<<gb, 256, 0, stream>>>(hbuf, img + 3 * 32768, bc, out, N);
}

// Round 7
// 293.655 us; speedup vs baseline: 1.9231x; 1.1127x over previous
//
#include <hip/hip_runtime.h>

typedef float f32x4 __attribute__((ext_vector_type(4)));
typedef short s16x8 __attribute__((ext_vector_type(8)));

// ---------- helpers ----------
__device__ __forceinline__ float us2f(unsigned short u) {
    union { unsigned int i; float f; } v;
    v.i = ((unsigned int)u) << 16;   // bf16 -> f32 exact
    return v.f;
}
__device__ __forceinline__ unsigned short f2us(float f) {
    union { unsigned int i; float f; } v; v.f = f;
    unsigned int r = v.i + 0x7fff + ((v.i >> 16) & 1);   // round-to-nearest-even
    return (unsigned short)(r >> 16);
}

// ================= CSR build: two-level bucket sort =================
__global__ void k_zero(int* __restrict__ bcnt) {        // 1 WG x 256
    bcnt[threadIdx.x] = 0;
}

__global__ __launch_bounds__(256) void k_hist(const int* __restrict__ dst, int E, int chunk,
                                              int* __restrict__ bcnt) {
    __shared__ int cnt[256];
    int t = threadIdx.x;
    cnt[t] = 0; __syncthreads();
    int s = blockIdx.x * chunk;
    int e = s + chunk; if (e > E) e = E;
    for (int i = s + t; i < e; i += 256) atomicAdd(&cnt[dst[i] >> 8], 1);
    __syncthreads();
    if (cnt[t]) atomicAdd(&bcnt[t], cnt[t]);
}

__global__ void k_bscan(const int* __restrict__ bcnt, int* __restrict__ bofs,
                        int* __restrict__ gcur) {
    __shared__ int s[256];
    int t = threadIdx.x;
    int v = bcnt[t];
    s[t] = v; __syncthreads();
    for (int off = 1; off < 256; off <<= 1) {
        int x = (t >= off) ? s[t - off] : 0;
        __syncthreads();
        s[t] += x;
        __syncthreads();
    }
    int ex = s[t] - v;
    bofs[t] = ex; gcur[t] = ex;
    if (t == 255) bofs[256] = s[255];
}

__global__ __launch_bounds__(256) void k_scatter1(const int* __restrict__ src,
                                                  const int* __restrict__ dst, int E, int chunk,
                                                  int* __restrict__ gcur,
                                                  unsigned int* __restrict__ pk) {
    __shared__ int cnt[256];
    int t = threadIdx.x;
    cnt[t] = 0; __syncthreads();
    int s = blockIdx.x * chunk;
    int e = s + chunk; if (e > E) e = E;
    for (int i = s + t; i < e; i += 256) atomicAdd(&cnt[dst[i] >> 8], 1);
    __syncthreads();
    int base = atomicAdd(&gcur[t], cnt[t]);
    cnt[t] = base;
    __syncthreads();
    for (int i = s + t; i < e; i += 256) {
        int d = dst[i];
        int slot = atomicAdd(&cnt[d >> 8], 1);
        pk[slot] = ((unsigned int)src[i] << 8) | (unsigned int)(d & 255);
    }
}

__global__ __launch_bounds__(256) void k_deg(const unsigned int* __restrict__ pk,
                                             const int* __restrict__ bofs,
                                             int* __restrict__ indeg, int N) {
    __shared__ int cnt[256];
    int t = threadIdx.x, b = blockIdx.x;
    cnt[t] = 0; __syncthreads();
    int s = bofs[b], e = bofs[b + 1];
    for (int i = s + t; i < e; i += 256) atomicAdd(&cnt[pk[i] & 255], 1);
    __syncthreads();
    int node = (b << 8) + t;
    if (node < N) indeg[node] = cnt[t];
}

__global__ void k_scan1(const int* __restrict__ indeg, int* __restrict__ row_ptr,
                        int* __restrict__ bsum, int N) {
    __shared__ int s[256];
    int t = threadIdx.x;
    int i = blockIdx.x * 256 + t;
    int v = (i < N) ? indeg[i] : 0;
    s[t] = v; __syncthreads();
    for (int off = 1; off < 256; off <<= 1) {
        int x = (t >= off) ? s[t - off] : 0;
        __syncthreads();
        s[t] += x;
        __syncthreads();
    }
    if (i < N) row_ptr[i] = s[t] - v;
    if (t == 255) bsum[blockIdx.x] = s[255];
}

__global__ void k_scan2(int* __restrict__ bsum, int nb) {  // nb <= 256
    __shared__ int s[256];
    int t = threadIdx.x;
    int v = (t < nb) ? bsum[t] : 0;
    s[t] = v; __syncthreads();
    for (int off = 1; off < 256; off <<= 1) {
        int x = (t >= off) ? s[t - off] : 0;
        __syncthreads();
        s[t] += x;
        __syncthreads();
    }
    if (t < nb) bsum[t] = s[t] - v;
}

__global__ void k_scan3(const int* __restrict__ indeg, int* __restrict__ row_ptr,
                        const int* __restrict__ bsum, float* __restrict__ dinv,
                        int N, int E) {
    int i = blockIdx.x * 256 + threadIdx.x;
    if (i < N) {
        row_ptr[i] += bsum[blockIdx.x];
        dinv[i] = rsqrtf((float)(indeg[i] + 1));   // +1 self-loop
    }
    if (i == 0) row_ptr[N] = E;
}

__global__ __launch_bounds__(256) void k_scatter2(const unsigned int* __restrict__ pk,
                                                  const int* __restrict__ bofs,
                                                  const int* __restrict__ row_ptr,
                                                  int* __restrict__ csr, int N) {
    __shared__ int cur[256];
    int t = threadIdx.x, b = blockIdx.x;
    int node = (b << 8) + t;
    cur[t] = (node < N) ? row_ptr[node] : 0;
    __syncthreads();
    int s = bofs[b], e = bofs[b + 1];
    for (int i = s + t; i < e; i += 256) {
        unsigned int v = pk[i];
        int slot = atomicAdd(&cur[v & 255], 1);
        csr[slot] = (int)(v >> 8);
    }
}

// ================= W prep: split fp32 weights into bf16 hi/lo images =================
// Image layout per weight (ushort units): idx(n,k) = n*128 + (((k>>3)^(n&15))<<3) + (k&7)
// XOR k-block swizzle -> conflict-free wave64 b128 fragment reads from LDS.
// img: [L0: H 16384, L 16384][L1][L2][Wc: H 6144, L 6144] (n padded 40->48, zeros)
// Fully parallel: one block per (layer, k-row); one element per thread.
__global__ void k_wprep(const float* __restrict__ W1, const float* __restrict__ W2,
                        const float* __restrict__ W3, const float* __restrict__ Wc,
                        unsigned short* __restrict__ img) {
    int b = blockIdx.x >> 7;         // layer 0..3
    int k = blockIdx.x & 127;        // k-row
    int n = threadIdx.x;
    unsigned short *H, *L;
    float f;
    if (b < 3) {
        const float* W = (b == 0) ? W1 : ((b == 1) ? W2 : W3);
        H = img + b * 32768; L = H + 16384;
        f = W[k * 128 + n];
    } else {
        if (n >= 48) return;
        H = img + 3 * 32768; L = H + 6144;
        f = (n < 40) ? Wc[k * 40 + n] : 0.f;
    }
    unsigned short h = f2us(f);
    unsigned short l = f2us(f - us2f(h));
    int idx = n * 128 + ((((k >> 3) ^ (n & 15))) << 3) + (k & 7);
    H[idx] = h; L[idx] = l;
}

// ================= MFMA GEMM: M[i][c] = bf16((A@W)[i][c] * dinv[i]) =================
// fp32 accuracy via bf16 hi/lo split: A@W = AhWh + AhWl + AlWh (err ~2^-16).
// Block = 64 rows, 4 waves x 16 rows. W image resident in LDS (64 KB, no k-loop
// barriers); A-frags straight from global with in-register hi/lo conversion.
__global__ __launch_bounds__(256) void k_gemm128m(const float* __restrict__ A,
                                                  const unsigned short* __restrict__ img,
                                                  const float* __restrict__ dinv,
                                                  unsigned short* __restrict__ M, int N) {
    __shared__ __align__(16) unsigned short WsH[16384];   // 32 KB
    __shared__ __align__(16) unsigned short WsL[16384];   // 32 KB
    int t = threadIdx.x;
    {
        const uint4* s = (const uint4*)img;
        uint4* dH = (uint4*)WsH; uint4* dL = (uint4*)WsL;
#pragma unroll
        for (int i = 0; i < 8; i++) dH[t + i * 256] = s[t + i * 256];
#pragma unroll
        for (int i = 0; i < 8; i++) dL[t + i * 256] = s[2048 + t + i * 256];
    }
    __syncthreads();

    int w = t >> 6, lane = t & 63;
    int m = lane & 15, q = lane >> 4;
    int row0 = blockIdx.x * 64 + w * 16;
    int gr = row0 + m;
    int grc = (gr < N) ? gr : (N - 1);
    const float4* Arow = (const float4*)(A + (size_t)grc * 128);
    int nbase = m * 128;

    f32x4 acc[8];
#pragma unroll
    for (int cb = 0; cb < 8; cb++) { acc[cb][0]=0.f; acc[cb][1]=0.f; acc[cb][2]=0.f; acc[cb][3]=0.f; }

#pragma unroll
    for (int ks = 0; ks < 4; ks++) {
        float4 f0 = Arow[ks * 8 + q * 2];
        float4 f1 = Arow[ks * 8 + q * 2 + 1];
        float fv[8] = {f0.x, f0.y, f0.z, f0.w, f1.x, f1.y, f1.z, f1.w};
        union { unsigned short u[8]; s16x8 v; } ah, al;
#pragma unroll
        for (int j = 0; j < 8; j++) {
            unsigned short h = f2us(fv[j]);
            ah.u[j] = h;
            al.u[j] = f2us(fv[j] - us2f(h));
        }
        int koff = (((ks * 4 + q) ^ m) & 15) << 3;
#pragma unroll
        for (int cb = 0; cb < 8; cb++) {
            int o = cb * 2048 + nbase + koff;
            s16x8 wh = *(const s16x8*)&WsH[o];
            s16x8 wl = *(const s16x8*)&WsL[o];
            acc[cb] = __builtin_amdgcn_mfma_f32_16x16x32_bf16(ah.v, wh, acc[cb], 0, 0, 0);
            acc[cb] = __builtin_amdgcn_mfma_f32_16x16x32_bf16(ah.v, wl, acc[cb], 0, 0, 0);
            acc[cb] = __builtin_amdgcn_mfma_f32_16x16x32_bf16(al.v, wh, acc[cb], 0, 0, 0);
        }
    }

#pragma unroll
    for (int r = 0; r < 4; r++) {
        int grow = row0 + q * 4 + r;
        if (grow < N) {
            float dv = dinv[grow];
#pragma unroll
            for (int cb = 0; cb < 8; cb++)
                M[(size_t)grow * 128 + cb * 16 + m] = f2us(acc[cb][r] * dv);
        }
    }
}

// ================= MFMA classifier: out = h3 @ Wc + bc (cols padded to 48) =========
__global__ __launch_bounds__(256) void k_gemm40m(const float* __restrict__ A,
                                                 const unsigned short* __restrict__ img,
                                                 const float* __restrict__ bc,
                                                 float* __restrict__ out, int N) {
    __shared__ __align__(16) unsigned short WsH[6144];    // 12 KB
    __shared__ __align__(16) unsigned short WsL[6144];    // 12 KB
    int t = threadIdx.x;
    {
        const uint4* s = (const uint4*)img;
        uint4* dH = (uint4*)WsH; uint4* dL = (uint4*)WsL;
#pragma unroll
        for (int i = 0; i < 3; i++) dH[t + i * 256] = s[t + i * 256];
#pragma unroll
        for (int i = 0; i < 3; i++) dL[t + i * 256] = s[768 + t + i * 256];
    }
    __syncthreads();

    int w = t >> 6, lane = t & 63;
    int m = lane & 15, q = lane >> 4;
    int row0 = blockIdx.x * 64 + w * 16;
    int gr = row0 + m;
    int grc = (gr < N) ? gr : (N - 1);
    const float4* Arow = (const float4*)(A + (size_t)grc * 128);
    int nbase = m * 128;

    f32x4 acc[3];
#pragma unroll
    for (int cb = 0; cb < 3; cb++) { acc[cb][0]=0.f; acc[cb][1]=0.f; acc[cb][2]=0.f; acc[cb][3]=0.f; }

#pragma unroll
    for (int ks = 0; ks < 4; ks++) {
        float4 f0 = Arow[ks * 8 + q * 2];
        float4 f1 = Arow[ks * 8 + q * 2 + 1];
        float fv[8] = {f0.x, f0.y, f0.z, f0.w, f1.x, f1.y, f1.z, f1.w};
        union { unsigned short u[8]; s16x8 v; } ah, al;
#pragma unroll
        for (int j = 0; j < 8; j++) {
            unsigned short h = f2us(fv[j]);
            ah.u[j] = h;
            al.u[j] = f2us(fv[j] - us2f(h));
        }
        int koff = (((ks * 4 + q) ^ m) & 15) << 3;
#pragma unroll
        for (int cb = 0; cb < 3; cb++) {
            int o = cb * 2048 + nbase + koff;
            s16x8 wh = *(const s16x8*)&WsH[o];
            s16x8 wl = *(const s16x8*)&WsL[o];
            acc[cb] = __builtin_amdgcn_mfma_f32_16x16x32_bf16(ah.v, wh, acc[cb], 0, 0, 0);
            acc[cb] = __builtin_amdgcn_mfma_f32_16x16x32_bf16(ah.v, wl, acc[cb], 0, 0, 0);
            acc[cb] = __builtin_amdgcn_mfma_f32_16x16x32_bf16(al.v, wh, acc[cb], 0, 0, 0);
        }
    }

#pragma unroll
    for (int r = 0; r < 4; r++) {
        int grow = row0 + q * 4 + r;
        if (grow < N) {
#pragma unroll
            for (int cb = 0; cb < 3; cb++) {
                int col = cb * 16 + m;
                if (col < 40) out[(size_t)grow * 40 + col] = acc[cb][r] + bc[col];
            }
        }
    }
}

// ---------- gather: H[v] = relu(dinv[v]*(m[v] + sum_{u->v} m[u]) + b) ----------
// one wave per node; lane = ushort2 of features; unroll-8 for MLP
__global__ __launch_bounds__(256) void k_gather(const unsigned short* __restrict__ M,
                                                const int* __restrict__ csr,
                                                const int* __restrict__ row_ptr,
                                                const float* __restrict__ dinv,
                                                const float* __restrict__ bias,
                                                float* __restrict__ H, int N) {
    int w    = (blockIdx.x << 2) + (threadIdx.x >> 6);
    int lane = threadIdx.x & 63;
    if (w >= N) return;

    const ushort2* M2 = (const ushort2*)M;   // row stride 64 ushort2
    float2 acc;
    {
        ushort2 p = M2[(size_t)w * 64 + lane];     // self term
        acc = make_float2(us2f(p.x), us2f(p.y));
    }
    int s0 = row_ptr[w], s1 = row_ptr[w + 1];

    for (int base = s0; base < s1; base += 64) {
        int n = s1 - base; if (n > 64) n = 64;
        int u = (lane < n) ? csr[base + lane] : 0;
        int j = 0;
        for (; j + 8 <= n; j += 8) {
            ushort2 tv[8];
#pragma unroll
            for (int i = 0; i < 8; i++) {
                int ui = __shfl(u, j + i);
                tv[i] = M2[(size_t)ui * 64 + lane];
            }
            float sx = 0.f, sy = 0.f;
#pragma unroll
            for (int i = 0; i < 8; i++) { sx += us2f(tv[i].x); sy += us2f(tv[i].y); }
            acc.x += sx; acc.y += sy;
        }
        for (; j < n; j++) {
            int uj = __shfl(u, j);
            ushort2 tj = M2[(size_t)uj * 64 + lane];
            acc.x += us2f(tj.x); acc.y += us2f(tj.y);
        }
    }

    float dv = dinv[w];
    float bx = bias[2 * lane], by = bias[2 * lane + 1];
    float ox = fmaxf(fmaf(dv, acc.x, bx), 0.f);
    float oy = fmaxf(fmaf(dv, acc.y, by), 0.f);
    ((float2*)H)[(size_t)w * 64 + lane] = make_float2(ox, oy);
}

// ---------- launch ----------
extern "C" void kernel_launch(void* const* d_in, const int* in_sizes, int n_in,
                              void* d_out, int out_size, void* d_ws, size_t ws_size,
                              hipStream_t stream) {
    const float* x  = (const float*)d_in[0];
    const int*   ei = (const int*)d_in[1];
    const float* W1 = (const float*)d_in[2];
    const float* b1 = (const float*)d_in[3];
    const float* W2 = (const float*)d_in[4];
    const float* b2 = (const float*)d_in[5];
    const float* W3 = (const float*)d_in[6];
    const float* b3 = (const float*)d_in[7];
    const float* Wc = (const float*)d_in[8];
    const float* bc = (const float*)d_in[9];

    const int N = in_sizes[0] / 128;   // 50000
    const int E = in_sizes[1] / 2;     // 800000
    const int* src = ei;
    const int* dst = ei + E;

    // workspace carve-out (~24.3 MB)
    char* ws = (char*)d_ws;
    size_t off = 0;
    auto alloc = [&](size_t bytes) -> void* {
        void* p = ws + off;
        off = (off + bytes + 255) & ~(size_t)255;
        return p;
    };
    unsigned short* Mbuf = (unsigned short*)alloc((size_t)N * 128 * 2);  // bf16
    unsigned int* pk     = (unsigned int*)alloc((size_t)E * 4);          // bucketed edges
    unsigned short* img  = (unsigned short*)alloc((3 * 32768 + 2 * 6144) * 2);
    float* dinv    = (float*)alloc((size_t)N * 4);
    int*   indeg   = (int*)alloc((size_t)N * 4);
    int*   row_ptr = (int*)alloc((size_t)(N + 1) * 4);
    int*   csr     = (int*)alloc((size_t)E * 4);
    int*   bcnt    = (int*)alloc(256 * 4);
    int*   bofs    = (int*)alloc(257 * 4);
    int*   gcur    = (int*)alloc(256 * 4);
    int*   bsum    = (int*)alloc(256 * 4);

    float* out  = (float*)d_out;               // logits [N,40]
    float* hbuf = out + (size_t)N * 40;        // h region [N,128] — reused for all layers

    const int nb  = (N + 255) / 256;   // 196 (<=256, required by k_scan2)
    const int NB  = (N + 255) >> 8;    // node buckets (196)
    const int G1  = 256;
    const int chunk = (E + G1 - 1) / G1;

    // weight prep (bf16 hi/lo swizzled images) — fully parallel
    k_wprep<<<512, 128, 0, stream>>>(W1, W2, W3, Wc, img);

    // CSR build: bucket sort (dst>>8) -> per-bucket degree + placement
    k_zero<<<1, 256, 0, stream>>>(bcnt);
    k_hist<<<G1, 256, 0, stream>>>(dst, E, chunk, bcnt);
    k_bscan<<<1, 256, 0, stream>>>(bcnt, bofs, gcur);
    k_scatter1<<<G1, 256, 0, stream>>>(src, dst, E, chunk, gcur, pk);
    k_deg<<<NB, 256, 0, stream>>>(pk, bofs, indeg, N);
    k_scan1<<<nb, 256, 0, stream>>>(indeg, row_ptr, bsum, N);
    k_scan2<<<1, 256, 0, stream>>>(bsum, nb);
    k_scan3<<<nb, 256, 0, stream>>>(indeg, row_ptr, bsum, dinv, N, E);
    k_scatter2<<<NB, 256, 0, stream>>>(pk, bofs, row_ptr, csr, N);

    const int gb  = (N + 63) / 64;    // gemm blocks (BM=64)
    const int gab = (N + 3) / 4;      // gather blocks (4 waves/block)

    // layer 1: x -> Mbuf(bf16) -> hbuf
    k_gemm128m<<<gb, 256, 0, stream>>>(x, img, dinv, Mbuf, N);
    k_gather<<<gab, 256, 0, stream>>>(Mbuf, csr, row_ptr, dinv, b1, hbuf, N);
    // layer 2
    k_gemm128m<<<gb, 256, 0, stream>>>(hbuf, img + 32768, dinv, Mbuf, N);
    k_gather<<<gab, 256, 0, stream>>>(Mbuf, csr, row_ptr, dinv, b2, hbuf, N);
    // layer 3: h3 -> d_out h-region
    k_gemm128m<<<gb, 256, 0, stream>>>(hbuf, img + 2 * 32768, dinv, Mbuf, N);
    k_gather<<<gab, 256, 0, stream>>>(Mbuf, csr, row_ptr, dinv, b3, hbuf, N);
    // classifier
    k_gemm40m<<<gb, 256, 0, stream>>>(hbuf, img + 3 * 32768, bc, out, N);
}

// Round 8
// 289.324 us; speedup vs baseline: 1.9519x; 1.0150x over previous
//
#include <hip/hip_runtime.h>

typedef float f32x4 __attribute__((ext_vector_type(4)));
typedef short s16x8 __attribute__((ext_vector_type(8)));

// ---------- helpers ----------
__device__ __forceinline__ float us2f(unsigned short u) {
    union { unsigned int i; float f; } v;
    v.i = ((unsigned int)u) << 16;   // bf16 -> f32 exact
    return v.f;
}
__device__ __forceinline__ unsigned short f2us(float f) {
    union { unsigned int i; float f; } v; v.f = f;
    unsigned int r = v.i + 0x7fff + ((v.i >> 16) & 1);   // round-to-nearest-even
    return (unsigned short)(r >> 16);
}

// ================= W prep + bcnt zero =================
// Image layout per weight (ushort units): idx(n,k) = n*128 + (((k>>3)^(n&15))<<3) + (k&7)
// XOR k-block swizzle -> conflict-free wave64 b128 fragment reads from LDS.
// img: [L0: H 16384, L 16384][L1][L2][Wc: H 6144, L 6144] (n padded 40->48, zeros)
// grid 513 x 128: blocks 0..511 = (layer,k-row); block 512 zeroes bcnt.
__global__ void k_wprep(const float* __restrict__ W1, const float* __restrict__ W2,
                        const float* __restrict__ W3, const float* __restrict__ Wc,
                        unsigned short* __restrict__ img, int* __restrict__ bcnt) {
    int b = blockIdx.x >> 7;         // layer 0..3, or 4 = bcnt-zero block
    int n = threadIdx.x;
    if (b >= 4) { bcnt[n] = 0; bcnt[n + 128] = 0; return; }
    int k = blockIdx.x & 127;        // k-row
    unsigned short *H, *L;
    float f;
    if (b < 3) {
        const float* W = (b == 0) ? W1 : ((b == 1) ? W2 : W3);
        H = img + b * 32768; L = H + 16384;
        f = W[k * 128 + n];
    } else {
        if (n >= 48) return;
        H = img + 3 * 32768; L = H + 6144;
        f = (n < 40) ? Wc[k * 40 + n] : 0.f;
    }
    unsigned short h = f2us(f);
    unsigned short l = f2us(f - us2f(h));
    int idx = n * 128 + ((((k >> 3) ^ (n & 15))) << 3) + (k & 7);
    H[idx] = h; L[idx] = l;
}

// ================= CSR build: two-level bucket sort =================
__global__ __launch_bounds__(256) void k_hist(const int* __restrict__ dst, int E, int chunk,
                                              int* __restrict__ bcnt) {
    __shared__ int cnt[256];
    int t = threadIdx.x;
    cnt[t] = 0; __syncthreads();
    int s = blockIdx.x * chunk;
    int e = s + chunk; if (e > E) e = E;
    for (int i = s + t; i < e; i += 256) atomicAdd(&cnt[dst[i] >> 8], 1);
    __syncthreads();
    if (cnt[t]) atomicAdd(&bcnt[t], cnt[t]);
}

__global__ void k_bscan(const int* __restrict__ bcnt, int* __restrict__ bofs,
                        int* __restrict__ gcur) {
    __shared__ int s[256];
    int t = threadIdx.x;
    int v = bcnt[t];
    s[t] = v; __syncthreads();
    for (int off = 1; off < 256; off <<= 1) {
        int x = (t >= off) ? s[t - off] : 0;
        __syncthreads();
        s[t] += x;
        __syncthreads();
    }
    int ex = s[t] - v;
    bofs[t] = ex; gcur[t] = ex;
    if (t == 255) bofs[256] = s[255];
}

__global__ __launch_bounds__(256) void k_scatter1(const int* __restrict__ src,
                                                  const int* __restrict__ dst, int E, int chunk,
                                                  int* __restrict__ gcur,
                                                  unsigned int* __restrict__ pk) {
    __shared__ int cnt[256];
    int t = threadIdx.x;
    cnt[t] = 0; __syncthreads();
    int s = blockIdx.x * chunk;
    int e = s + chunk; if (e > E) e = E;
    for (int i = s + t; i < e; i += 256) atomicAdd(&cnt[dst[i] >> 8], 1);
    __syncthreads();
    int base = atomicAdd(&gcur[t], cnt[t]);
    cnt[t] = base;
    __syncthreads();
    for (int i = s + t; i < e; i += 256) {
        int d = dst[i];
        int slot = atomicAdd(&cnt[d >> 8], 1);
        pk[slot] = ((unsigned int)src[i] << 8) | (unsigned int)(d & 255);
    }
}

// per-bucket in-degree histogram + fused block-local exclusive scan + dinv.
// A bucket (256 nodes) is exactly one scan block.
__global__ __launch_bounds__(256) void k_degscan(const unsigned int* __restrict__ pk,
                                                 const int* __restrict__ bofs,
                                                 int* __restrict__ row_ptr,
                                                 int* __restrict__ bsum,
                                                 float* __restrict__ dinv, int N) {
    __shared__ int cnt[256];
    __shared__ int s[256];
    int t = threadIdx.x, b = blockIdx.x;
    cnt[t] = 0; __syncthreads();
    int s0 = bofs[b], s1 = bofs[b + 1];
    for (int i = s0 + t; i < s1; i += 256) atomicAdd(&cnt[pk[i] & 255], 1);
    __syncthreads();
    int v = cnt[t];
    s[t] = v; __syncthreads();
    for (int off = 1; off < 256; off <<= 1) {
        int x = (t >= off) ? s[t - off] : 0;
        __syncthreads();
        s[t] += x;
        __syncthreads();
    }
    int node = (b << 8) + t;
    if (node < N) {
        row_ptr[node] = s[t] - v;                 // exclusive within bucket
        dinv[node] = rsqrtf((float)(v + 1));      // +1 self-loop
    }
    if (t == 255) bsum[b] = s[255];
}

__global__ void k_scan2(int* __restrict__ bsum, int nb) {  // nb <= 256
    __shared__ int s[256];
    int t = threadIdx.x;
    int v = (t < nb) ? bsum[t] : 0;
    s[t] = v; __syncthreads();
    for (int off = 1; off < 256; off <<= 1) {
        int x = (t >= off) ? s[t - off] : 0;
        __syncthreads();
        s[t] += x;
        __syncthreads();
    }
    if (t < nb) bsum[t] = s[t] - v;
}

__global__ void k_scan3(int* __restrict__ row_ptr, const int* __restrict__ bsum,
                        int N, int E) {
    int i = blockIdx.x * 256 + threadIdx.x;
    if (i < N) row_ptr[i] += bsum[blockIdx.x];
    if (i == 0) row_ptr[N] = E;
}

__global__ __launch_bounds__(256) void k_scatter2(const unsigned int* __restrict__ pk,
                                                  const int* __restrict__ bofs,
                                                  const int* __restrict__ row_ptr,
                                                  int* __restrict__ csr, int N) {
    __shared__ int cur[256];
    int t = threadIdx.x, b = blockIdx.x;
    int node = (b << 8) + t;
    cur[t] = (node < N) ? row_ptr[node] : 0;
    __syncthreads();
    int s = bofs[b], e = bofs[b + 1];
    for (int i = s + t; i < e; i += 256) {
        unsigned int v = pk[i];
        int slot = atomicAdd(&cur[v & 255], 1);
        csr[slot] = (int)(v >> 8);
    }
}

// ================= MFMA GEMM: M[i][c] = bf16((A@W)[i][c] * dinv[i]) =================
// fp32 accuracy via bf16 hi/lo split: A@W = AhWh + AhWl + AlWh (err ~2^-16).
// Block = 64 rows, 4 waves x 16 rows. W image resident in LDS (64 KB, no k-loop
// barriers); A-frags straight from global with in-register hi/lo conversion.
__global__ __launch_bounds__(256) void k_gemm128m(const float* __restrict__ A,
                                                  const unsigned short* __restrict__ img,
                                                  const float* __restrict__ dinv,
                                                  unsigned short* __restrict__ M, int N) {
    __shared__ __align__(16) unsigned short WsH[16384];   // 32 KB
    __shared__ __align__(16) unsigned short WsL[16384];   // 32 KB
    int t = threadIdx.x;
    {
        const uint4* s = (const uint4*)img;
        uint4* dH = (uint4*)WsH; uint4* dL = (uint4*)WsL;
#pragma unroll
        for (int i = 0; i < 8; i++) dH[t + i * 256] = s[t + i * 256];
#pragma unroll
        for (int i = 0; i < 8; i++) dL[t + i * 256] = s[2048 + t + i * 256];
    }
    __syncthreads();

    int w = t >> 6, lane = t & 63;
    int m = lane & 15, q = lane >> 4;
    int row0 = blockIdx.x * 64 + w * 16;
    int gr = row0 + m;
    int grc = (gr < N) ? gr : (N - 1);
    const float4* Arow = (const float4*)(A + (size_t)grc * 128);
    int nbase = m * 128;

    f32x4 acc[8];
#pragma unroll
    for (int cb = 0; cb < 8; cb++) { acc[cb][0]=0.f; acc[cb][1]=0.f; acc[cb][2]=0.f; acc[cb][3]=0.f; }

#pragma unroll
    for (int ks = 0; ks < 4; ks++) {
        float4 f0 = Arow[ks * 8 + q * 2];
        float4 f1 = Arow[ks * 8 + q * 2 + 1];
        float fv[8] = {f0.x, f0.y, f0.z, f0.w, f1.x, f1.y, f1.z, f1.w};
        union { unsigned short u[8]; s16x8 v; } ah, al;
#pragma unroll
        for (int j = 0; j < 8; j++) {
            unsigned short h = f2us(fv[j]);
            ah.u[j] = h;
            al.u[j] = f2us(fv[j] - us2f(h));
        }
        int koff = (((ks * 4 + q) ^ m) & 15) << 3;
#pragma unroll
        for (int cb = 0; cb < 8; cb++) {
            int o = cb * 2048 + nbase + koff;
            s16x8 wh = *(const s16x8*)&WsH[o];
            s16x8 wl = *(const s16x8*)&WsL[o];
            acc[cb] = __builtin_amdgcn_mfma_f32_16x16x32_bf16(ah.v, wh, acc[cb], 0, 0, 0);
            acc[cb] = __builtin_amdgcn_mfma_f32_16x16x32_bf16(ah.v, wl, acc[cb], 0, 0, 0);
            acc[cb] = __builtin_amdgcn_mfma_f32_16x16x32_bf16(al.v, wh, acc[cb], 0, 0, 0);
        }
    }

#pragma unroll
    for (int r = 0; r < 4; r++) {
        int grow = row0 + q * 4 + r;
        if (grow < N) {
            float dv = dinv[grow];
#pragma unroll
            for (int cb = 0; cb < 8; cb++)
                M[(size_t)grow * 128 + cb * 16 + m] = f2us(acc[cb][r] * dv);
        }
    }
}

// ================= MFMA classifier: out = h3 @ Wc + bc (cols padded to 48) =========
__global__ __launch_bounds__(256) void k_gemm40m(const float* __restrict__ A,
                                                 const unsigned short* __restrict__ img,
                                                 const float* __restrict__ bc,
                                                 float* __restrict__ out, int N) {
    __shared__ __align__(16) unsigned short WsH[6144];    // 12 KB
    __shared__ __align__(16) unsigned short WsL[6144];    // 12 KB
    int t = threadIdx.x;
    {
        const uint4* s = (const uint4*)img;
        uint4* dH = (uint4*)WsH; uint4* dL = (uint4*)WsL;
#pragma unroll
        for (int i = 0; i < 3; i++) dH[t + i * 256] = s[t + i * 256];
#pragma unroll
        for (int i = 0; i < 3; i++) dL[t + i * 256] = s[768 + t + i * 256];
    }
    __syncthreads();

    int w = t >> 6, lane = t & 63;
    int m = lane & 15, q = lane >> 4;
    int row0 = blockIdx.x * 64 + w * 16;
    int gr = row0 + m;
    int grc = (gr < N) ? gr : (N - 1);
    const float4* Arow = (const float4*)(A + (size_t)grc * 128);
    int nbase = m * 128;

    f32x4 acc[3];
#pragma unroll
    for (int cb = 0; cb < 3; cb++) { acc[cb][0]=0.f; acc[cb][1]=0.f; acc[cb][2]=0.f; acc[cb][3]=0.f; }

#pragma unroll
    for (int ks = 0; ks < 4; ks++) {
        float4 f0 = Arow[ks * 8 + q * 2];
        float4 f1 = Arow[ks * 8 + q * 2 + 1];
        float fv[8] = {f0.x, f0.y, f0.z, f0.w, f1.x, f1.y, f1.z, f1.w};
        union { unsigned short u[8]; s16x8 v; } ah, al;
#pragma unroll
        for (int j = 0; j < 8; j++) {
            unsigned short h = f2us(fv[j]);
            ah.u[j] = h;
            al.u[j] = f2us(fv[j] - us2f(h));
        }
        int koff = (((ks * 4 + q) ^ m) & 15) << 3;
#pragma unroll
        for (int cb = 0; cb < 3; cb++) {
            int o = cb * 2048 + nbase + koff;
            s16x8 wh = *(const s16x8*)&WsH[o];
            s16x8 wl = *(const s16x8*)&WsL[o];
            acc[cb] = __builtin_amdgcn_mfma_f32_16x16x32_bf16(ah.v, wh, acc[cb], 0, 0, 0);
            acc[cb] = __builtin_amdgcn_mfma_f32_16x16x32_bf16(ah.v, wl, acc[cb], 0, 0, 0);
            acc[cb] = __builtin_amdgcn_mfma_f32_16x16x32_bf16(al.v, wh, acc[cb], 0, 0, 0);
        }
    }

#pragma unroll
    for (int r = 0; r < 4; r++) {
        int grow = row0 + q * 4 + r;
        if (grow < N) {
#pragma unroll
            for (int cb = 0; cb < 3; cb++) {
                int col = cb * 16 + m;
                if (col < 40) out[(size_t)grow * 40 + col] = acc[cb][r] + bc[col];
            }
        }
    }
}

// ---------- gather: H[v] = relu(dinv[v]*(m[v] + sum_{u->v} m[u]) + b) ----------
// one wave per node; lane = ushort2 of features; bf16 M rows (256 B); unroll-4
__global__ __launch_bounds__(256) void k_gather(const unsigned short* __restrict__ M,
                                                const int* __restrict__ csr,
                                                const int* __restrict__ row_ptr,
                                                const float* __restrict__ dinv,
                                                const float* __restrict__ bias,
                                                float* __restrict__ H, int N) {
    int w    = (blockIdx.x << 2) + (threadIdx.x >> 6);
    int lane = threadIdx.x & 63;
    if (w >= N) return;

    const ushort2* M2 = (const ushort2*)M;   // row stride 64 ushort2
    float2 acc;
    {
        ushort2 p = M2[(size_t)w * 64 + lane];     // self term
        acc = make_float2(us2f(p.x), us2f(p.y));
    }
    int s0 = row_ptr[w], s1 = row_ptr[w + 1];

    for (int base = s0; base < s1; base += 64) {
        int n = s1 - base; if (n > 64) n = 64;
        int u = (lane < n) ? csr[base + lane] : 0;
        int j = 0;
        for (; j + 4 <= n; j += 4) {
            int u0 = __shfl(u, j), u1 = __shfl(u, j + 1);
            int u2 = __shfl(u, j + 2), u3 = __shfl(u, j + 3);
            ushort2 t0 = M2[(size_t)u0 * 64 + lane];
            ushort2 t1 = M2[(size_t)u1 * 64 + lane];
            ushort2 t2 = M2[(size_t)u2 * 64 + lane];
            ushort2 t3 = M2[(size_t)u3 * 64 + lane];
            acc.x += (us2f(t0.x) + us2f(t1.x)) + (us2f(t2.x) + us2f(t3.x));
            acc.y += (us2f(t0.y) + us2f(t1.y)) + (us2f(t2.y) + us2f(t3.y));
        }
        for (; j < n; j++) {
            int uj = __shfl(u, j);
            ushort2 tj = M2[(size_t)uj * 64 + lane];
            acc.x += us2f(tj.x); acc.y += us2f(tj.y);
        }
    }

    float dv = dinv[w];
    float bx = bias[2 * lane], by = bias[2 * lane + 1];
    float ox = fmaxf(fmaf(dv, acc.x, bx), 0.f);
    float oy = fmaxf(fmaf(dv, acc.y, by), 0.f);
    ((float2*)H)[(size_t)w * 64 + lane] = make_float2(ox, oy);
}

// ---------- launch ----------
extern "C" void kernel_launch(void* const* d_in, const int* in_sizes, int n_in,
                              void* d_out, int out_size, void* d_ws, size_t ws_size,
                              hipStream_t stream) {
    const float* x  = (const float*)d_in[0];
    const int*   ei = (const int*)d_in[1];
    const float* W1 = (const float*)d_in[2];
    const float* b1 = (const float*)d_in[3];
    const float* W2 = (const float*)d_in[4];
    const float* b2 = (const float*)d_in[5];
    const float* W3 = (const float*)d_in[6];
    const float* b3 = (const float*)d_in[7];
    const float* Wc = (const float*)d_in[8];
    const float* bc = (const float*)d_in[9];

    const int N = in_sizes[0] / 128;   // 50000
    const int E = in_sizes[1] / 2;     // 800000
    const int* src = ei;
    const int* dst = ei + E;

    // workspace carve-out (~24 MB)
    char* ws = (char*)d_ws;
    size_t off = 0;
    auto alloc = [&](size_t bytes) -> void* {
        void* p = ws + off;
        off = (off + bytes + 255) & ~(size_t)255;
        return p;
    };
    unsigned short* Mbuf = (unsigned short*)alloc((size_t)N * 128 * 2);  // bf16
    unsigned int* pk     = (unsigned int*)alloc((size_t)E * 4);          // bucketed edges
    unsigned short* img  = (unsigned short*)alloc((3 * 32768 + 2 * 6144) * 2);
    float* dinv    = (float*)alloc((size_t)N * 4);
    int*   row_ptr = (int*)alloc((size_t)(N + 1) * 4);
    int*   csr     = (int*)alloc((size_t)E * 4);
    int*   bcnt    = (int*)alloc(256 * 4);
    int*   bofs    = (int*)alloc(257 * 4);
    int*   gcur    = (int*)alloc(256 * 4);
    int*   bsum    = (int*)alloc(256 * 4);

    float* out  = (float*)d_out;               // logits [N,40]
    float* hbuf = out + (size_t)N * 40;        // h region [N,128] — reused for all layers

    const int nb  = (N + 255) / 256;   // 196 (<=256, required by k_scan2)
    const int NB  = (N + 255) >> 8;    // node buckets (196)
    const int G1  = 256;
    const int chunk = (E + G1 - 1) / G1;

    // weight prep (bf16 hi/lo swizzled images) + bcnt zero (block 512)
    k_wprep<<<513, 128, 0, stream>>>(W1, W2, W3, Wc, img, bcnt);

    // CSR build: bucket sort (dst>>8) -> per-bucket degree+scan -> placement
    k_hist<<<G1, 256, 0, stream>>>(dst, E, chunk, bcnt);
    k_bscan<<<1, 256, 0, stream>>>(bcnt, bofs, gcur);
    k_scatter1<<<G1, 256, 0, stream>>>(src, dst, E, chunk, gcur, pk);
    k_degscan<<<NB, 256, 0, stream>>>(pk, bofs, row_ptr, bsum, dinv, N);
    k_scan2<<<1, 256, 0, stream>>>(bsum, nb);
    k_scan3<<<nb, 256, 0, stream>>>(row_ptr, bsum, N, E);
    k_scatter2<<<NB, 256, 0, stream>>>(pk, bofs, row_ptr, csr, N);

    const int gb  = (N + 63) / 64;    // gemm blocks (BM=64)
    const int gab = (N + 3) / 4;      // gather blocks (4 waves/block)

    // layer 1: x -> Mbuf(bf16) -> hbuf
    k_gemm128m<<<gb, 256, 0, stream>>>(x, img, dinv, Mbuf, N);
    k_gather<<<gab, 256, 0, stream>>>(Mbuf, csr, row_ptr, dinv, b1, hbuf, N);
    // layer 2
    k_gemm128m<<<gb, 256, 0, stream>>>(hbuf, img + 32768, dinv, Mbuf, N);
    k_gather<<<gab, 256, 0, stream>>>(Mbuf, csr, row_ptr, dinv, b2, hbuf, N);
    // layer 3: h3 -> d_out h-region
    k_gemm128m<<<gb, 256, 0, stream>>>(hbuf, img + 2 * 32768, dinv, Mbuf, N);
    k_gather<<<gab, 256, 0, stream>>>(Mbuf, csr, row_ptr, dinv, b3, hbuf, N);
    // classifier
    k_gemm40m<<<gb, 256, 0, stream>>>(hbuf, img + 3 * 32768, bc, out, N);
}

// Round 10
// 285.128 us; speedup vs baseline: 1.9806x; 1.0147x over previous
//
#include <hip/hip_runtime.h>

typedef float f32x4 __attribute__((ext_vector_type(4)));
typedef short s16x8 __attribute__((ext_vector_type(8)));

// ---------- helpers ----------
__device__ __forceinline__ float us2f(unsigned short u) {
    union { unsigned int i; float f; } v;
    v.i = ((unsigned int)u) << 16;   // bf16 -> f32 exact
    return v.f;
}
__device__ __forceinline__ unsigned short f2us(float f) {
    union { unsigned int i; float f; } v; v.f = f;
    unsigned int r = v.i + 0x7fff + ((v.i >> 16) & 1);   // round-to-nearest-even
    return (unsigned short)(r >> 16);
}

// ================= W prep + bcnt zero =================
// Image layout per weight (ushort units): idx(n,k) = n*128 + (((k>>3)^(n&15))<<3) + (k&7)
// grid 513 x 128: blocks 0..511 = (layer,k-row); block 512 zeroes bcnt.
__global__ void k_wprep(const float* __restrict__ W1, const float* __restrict__ W2,
                        const float* __restrict__ W3, const float* __restrict__ Wc,
                        unsigned short* __restrict__ img, int* __restrict__ bcnt) {
    int b = blockIdx.x >> 7;         // layer 0..3, or 4 = bcnt-zero block
    int n = threadIdx.x;
    if (b >= 4) { bcnt[n] = 0; bcnt[n + 128] = 0; return; }
    int k = blockIdx.x & 127;        // k-row
    unsigned short *H, *L;
    float f;
    if (b < 3) {
        const float* W = (b == 0) ? W1 : ((b == 1) ? W2 : W3);
        H = img + b * 32768; L = H + 16384;
        f = W[k * 128 + n];
    } else {
        if (n >= 48) return;
        H = img + 3 * 32768; L = H + 6144;
        f = (n < 40) ? Wc[k * 40 + n] : 0.f;
    }
    unsigned short h = f2us(f);
    unsigned short l = f2us(f - us2f(h));
    int idx = n * 128 + ((((k >> 3) ^ (n & 15))) << 3) + (k & 7);
    H[idx] = h; L[idx] = l;
}

// ================= CSR build: two-level bucket sort =================
__global__ __launch_bounds__(256) void k_hist(const int* __restrict__ dst, int E, int chunk,
                                              int* __restrict__ bcnt) {
    __shared__ int cnt[256];
    int t = threadIdx.x;
    cnt[t] = 0; __syncthreads();
    int s = blockIdx.x * chunk;
    int e = s + chunk; if (e > E) e = E;
    for (int i = s + t; i < e; i += 256) atomicAdd(&cnt[dst[i] >> 8], 1);
    __syncthreads();
    if (cnt[t]) atomicAdd(&bcnt[t], cnt[t]);
}

__global__ void k_bscan(const int* __restrict__ bcnt, int* __restrict__ bofs,
                        int* __restrict__ gcur) {
    __shared__ int s[256];
    int t = threadIdx.x;
    int v = bcnt[t];
    s[t] = v; __syncthreads();
    for (int off = 1; off < 256; off <<= 1) {
        int x = (t >= off) ? s[t - off] : 0;
        __syncthreads();
        s[t] += x;
        __syncthreads();
    }
    int ex = s[t] - v;
    bofs[t] = ex; gcur[t] = ex;
    if (t == 255) bofs[256] = s[255];
}

__global__ __launch_bounds__(256) void k_scatter1(const int* __restrict__ src,
                                                  const int* __restrict__ dst, int E, int chunk,
                                                  int* __restrict__ gcur,
                                                  unsigned int* __restrict__ pk) {
    __shared__ int cnt[256];
    int t = threadIdx.x;
    cnt[t] = 0; __syncthreads();
    int s = blockIdx.x * chunk;
    int e = s + chunk; if (e > E) e = E;
    for (int i = s + t; i < e; i += 256) atomicAdd(&cnt[dst[i] >> 8], 1);
    __syncthreads();
    int base = atomicAdd(&gcur[t], cnt[t]);
    cnt[t] = base;
    __syncthreads();
    for (int i = s + t; i < e; i += 256) {
        int d = dst[i];
        int slot = atomicAdd(&cnt[d >> 8], 1);
        pk[slot] = ((unsigned int)src[i] << 8) | (unsigned int)(d & 255);
    }
}

// per-bucket in-degree histogram + fused block-local exclusive scan + dinv
__global__ __launch_bounds__(256) void k_degscan(const unsigned int* __restrict__ pk,
                                                 const int* __restrict__ bofs,
                                                 int* __restrict__ row_ptr,
                                                 int* __restrict__ bsum,
                                                 float* __restrict__ dinv, int N) {
    __shared__ int cnt[256];
    __shared__ int s[256];
    int t = threadIdx.x, b = blockIdx.x;
    cnt[t] = 0; __syncthreads();
    int s0 = bofs[b], s1 = bofs[b + 1];
    for (int i = s0 + t; i < s1; i += 256) atomicAdd(&cnt[pk[i] & 255], 1);
    __syncthreads();
    int v = cnt[t];
    s[t] = v; __syncthreads();
    for (int off = 1; off < 256; off <<= 1) {
        int x = (t >= off) ? s[t - off] : 0;
        __syncthreads();
        s[t] += x;
        __syncthreads();
    }
    int node = (b << 8) + t;
    if (node < N) {
        row_ptr[node] = s[t] - v;                 // exclusive within bucket
        dinv[node] = rsqrtf((float)(v + 1));      // +1 self-loop
    }
    if (t == 255) bsum[b] = s[255];
}

__global__ void k_scan2(int* __restrict__ bsum, int nb) {  // nb <= 256
    __shared__ int s[256];
    int t = threadIdx.x;
    int v = (t < nb) ? bsum[t] : 0;
    s[t] = v; __syncthreads();
    for (int off = 1; off < 256; off <<= 1) {
        int x = (t >= off) ? s[t - off] : 0;
        __syncthreads();
        s[t] += x;
        __syncthreads();
    }
    if (t < nb) bsum[t] = s[t] - v;
}

// placement + row_ptr finalization (scan3 folded in)
__global__ __launch_bounds__(256) void k_scatter2(const unsigned int* __restrict__ pk,
                                                  const int* __restrict__ bofs,
                                                  int* __restrict__ row_ptr,
                                                  const int* __restrict__ bsum,
                                                  int* __restrict__ csr, int N, int E) {
    __shared__ int cur[256];
    int t = threadIdx.x, b = blockIdx.x;
    int node = (b << 8) + t;
    int rp = 0;
    if (node < N) {
        rp = row_ptr[node] + bsum[b];
        row_ptr[node] = rp;                       // finalize for gather
    }
    cur[t] = rp;
    __syncthreads();
    int s = bofs[b], e = bofs[b + 1];
    for (int i = s + t; i < e; i += 256) {
        unsigned int v = pk[i];
        int slot = atomicAdd(&cur[v & 255], 1);
        csr[slot] = (int)(v >> 8);
    }
    if (node == N - 1) row_ptr[N] = E;
}

// ================= MFMA GEMM: M[i][c] = bf16((A@W)[i][c] * dinv[i]) =================
__global__ __launch_bounds__(256) void k_gemm128m(const float* __restrict__ A,
                                                  const unsigned short* __restrict__ img,
                                                  const float* __restrict__ dinv,
                                                  unsigned short* __restrict__ M, int N) {
    __shared__ __align__(16) unsigned short WsH[16384];   // 32 KB
    __shared__ __align__(16) unsigned short WsL[16384];   // 32 KB
    int t = threadIdx.x;
    {
        const uint4* s = (const uint4*)img;
        uint4* dH = (uint4*)WsH; uint4* dL = (uint4*)WsL;
#pragma unroll
        for (int i = 0; i < 8; i++) dH[t + i * 256] = s[t + i * 256];
#pragma unroll
        for (int i = 0; i < 8; i++) dL[t + i * 256] = s[2048 + t + i * 256];
    }
    __syncthreads();

    int w = t >> 6, lane = t & 63;
    int m = lane & 15, q = lane >> 4;
    int row0 = blockIdx.x * 64 + w * 16;
    int gr = row0 + m;
    int grc = (gr < N) ? gr : (N - 1);
    const float4* Arow = (const float4*)(A + (size_t)grc * 128);
    int nbase = m * 128;

    f32x4 acc[8];
#pragma unroll
    for (int cb = 0; cb < 8; cb++) { acc[cb][0]=0.f; acc[cb][1]=0.f; acc[cb][2]=0.f; acc[cb][3]=0.f; }

#pragma unroll
    for (int ks = 0; ks < 4; ks++) {
        float4 f0 = Arow[ks * 8 + q * 2];
        float4 f1 = Arow[ks * 8 + q * 2 + 1];
        float fv[8] = {f0.x, f0.y, f0.z, f0.w, f1.x, f1.y, f1.z, f1.w};
        union { unsigned short u[8]; s16x8 v; } ah, al;
#pragma unroll
        for (int j = 0; j < 8; j++) {
            unsigned short h = f2us(fv[j]);
            ah.u[j] = h;
            al.u[j] = f2us(fv[j] - us2f(h));
        }
        int koff = (((ks * 4 + q) ^ m) & 15) << 3;
#pragma unroll
        for (int cb = 0; cb < 8; cb++) {
            int o = cb * 2048 + nbase + koff;
            s16x8 wh = *(const s16x8*)&WsH[o];
            s16x8 wl = *(const s16x8*)&WsL[o];
            acc[cb] = __builtin_amdgcn_mfma_f32_16x16x32_bf16(ah.v, wh, acc[cb], 0, 0, 0);
            acc[cb] = __builtin_amdgcn_mfma_f32_16x16x32_bf16(ah.v, wl, acc[cb], 0, 0, 0);
            acc[cb] = __builtin_amdgcn_mfma_f32_16x16x32_bf16(al.v, wh, acc[cb], 0, 0, 0);
        }
    }

#pragma unroll
    for (int r = 0; r < 4; r++) {
        int grow = row0 + q * 4 + r;
        if (grow < N) {
            float dv = dinv[grow];
#pragma unroll
            for (int cb = 0; cb < 8; cb++)
                M[(size_t)grow * 128 + cb * 16 + m] = f2us(acc[cb][r] * dv);
        }
    }
}

// ================= MFMA classifier: out = h3 @ Wc + bc (cols padded to 48) =========
__global__ __launch_bounds__(256) void k_gemm40m(const float* __restrict__ A,
                                                 const unsigned short* __restrict__ img,
                                                 const float* __restrict__ bc,
                                                 float* __restrict__ out, int N) {
    __shared__ __align__(16) unsigned short WsH[6144];    // 12 KB
    __shared__ __align__(16) unsigned short WsL[6144];    // 12 KB
    int t = threadIdx.x;
    {
        const uint4* s = (const uint4*)img;
        uint4* dH = (uint4*)WsH; uint4* dL = (uint4*)WsL;
#pragma unroll
        for (int i = 0; i < 3; i++) dH[t + i * 256] = s[t + i * 256];
#pragma unroll
        for (int i = 0; i < 3; i++) dL[t + i * 256] = s[768 + t + i * 256];
    }
    __syncthreads();

    int w = t >> 6, lane = t & 63;
    int m = lane & 15, q = lane >> 4;
    int row0 = blockIdx.x * 64 + w * 16;
    int gr = row0 + m;
    int grc = (gr < N) ? gr : (N - 1);
    const float4* Arow = (const float4*)(A + (size_t)grc * 128);
    int nbase = m * 128;

    f32x4 acc[3];
#pragma unroll
    for (int cb = 0; cb < 3; cb++) { acc[cb][0]=0.f; acc[cb][1]=0.f; acc[cb][2]=0.f; acc[cb][3]=0.f; }

#pragma unroll
    for (int ks = 0; ks < 4; ks++) {
        float4 f0 = Arow[ks * 8 + q * 2];
        float4 f1 = Arow[ks * 8 + q * 2 + 1];
        float fv[8] = {f0.x, f0.y, f0.z, f0.w, f1.x, f1.y, f1.z, f1.w};
        union { unsigned short u[8]; s16x8 v; } ah, al;
#pragma unroll
        for (int j = 0; j < 8; j++) {
            unsigned short h = f2us(fv[j]);
            ah.u[j] = h;
            al.u[j] = f2us(fv[j] - us2f(h));
        }
        int koff = (((ks * 4 + q) ^ m) & 15) << 3;
#pragma unroll
        for (int cb = 0; cb < 3; cb++) {
            int o = cb * 2048 + nbase + koff;
            s16x8 wh = *(const s16x8*)&WsH[o];
            s16x8 wl = *(const s16x8*)&WsL[o];
            acc[cb] = __builtin_amdgcn_mfma_f32_16x16x32_bf16(ah.v, wh, acc[cb], 0, 0, 0);
            acc[cb] = __builtin_amdgcn_mfma_f32_16x16x32_bf16(ah.v, wl, acc[cb], 0, 0, 0);
            acc[cb] = __builtin_amdgcn_mfma_f32_16x16x32_bf16(al.v, wh, acc[cb], 0, 0, 0);
        }
    }

#pragma unroll
    for (int r = 0; r < 4; r++) {
        int grow = row0 + q * 4 + r;
        if (grow < N) {
#pragma unroll
            for (int cb = 0; cb < 3; cb++) {
                int col = cb * 16 + m;
                if (col < 40) out[(size_t)grow * 40 + col] = acc[cb][r] + bc[col];
            }
        }
    }
}

// ---------- gather v2: H[v] = relu(dinv[v]*(m[v] + sum_{u->v} m[u]) + b) ----------
// one wave per node; 4 lane-groups of 16; each wave-instruction fetches FOUR
// neighbor rows (16 lanes x 16 B = one 256 B bf16 row per group).
// ALL __shfl broadcasts execute full-wave (ds_bpermute from an inactive lane is
// undefined — the round-9 bug); only the accumulate is predicated.
__global__ __launch_bounds__(256) void k_gather(const unsigned short* __restrict__ M,
                                                const int* __restrict__ csr,
                                                const int* __restrict__ row_ptr,
                                                const float* __restrict__ dinv,
                                                const float* __restrict__ bias,
                                                float* __restrict__ H, int N) {
    int w    = (blockIdx.x << 2) + (threadIdx.x >> 6);
    int lane = threadIdx.x & 63;
    if (w >= N) return;
    int g  = lane >> 4;      // neighbor group 0..3
    int sl = lane & 15;      // 16 B slot within row

    const uint4* M16 = (const uint4*)M;    // row = 16 uint4 (256 B)
    float acc[8];
#pragma unroll
    for (int i = 0; i < 8; i++) acc[i] = 0.f;

    auto accum = [&](uint4 tv) {
        unsigned int uu[4] = {tv.x, tv.y, tv.z, tv.w};
#pragma unroll
        for (int i = 0; i < 4; i++) {
            acc[2 * i]     += us2f((unsigned short)(uu[i] & 0xffffu));
            acc[2 * i + 1] += us2f((unsigned short)(uu[i] >> 16));
        }
    };

    if (g == 0) accum(M16[(size_t)w * 16 + sl]);   // self term (once)

    int s0 = row_ptr[w], s1 = row_ptr[w + 1];
    for (int base = s0; base < s1; base += 64) {
        int n = s1 - base; if (n > 64) n = 64;
        int idx = (lane < n) ? csr[base + lane] : 0;
        int full = n >> 2;
        int rem  = n & 3;
        int j = 0;
        for (; j + 4 <= full; j += 4) {            // full-wave shfls
            int u0 = __shfl(idx, (j + 0) * 4 + g);
            int u1 = __shfl(idx, (j + 1) * 4 + g);
            int u2 = __shfl(idx, (j + 2) * 4 + g);
            int u3 = __shfl(idx, (j + 3) * 4 + g);
            uint4 t0 = M16[(size_t)u0 * 16 + sl];
            uint4 t1 = M16[(size_t)u1 * 16 + sl];
            uint4 t2 = M16[(size_t)u2 * 16 + sl];
            uint4 t3 = M16[(size_t)u3 * 16 + sl];
            accum(t0); accum(t1); accum(t2); accum(t3);
        }
        for (; j < full; j++) {                    // full-wave shfl
            int u = __shfl(idx, j * 4 + g);
            accum(M16[(size_t)u * 16 + sl]);
        }
        // remainder: shfl hoisted OUT of divergence (full-wave), accum guarded
        int ur = __shfl(idx, ((full << 2) + g) & 63);
        if (g < rem) accum(M16[(size_t)ur * 16 + sl]);
    }

    // reduce across the 4 groups (full-wave)
#pragma unroll
    for (int i = 0; i < 8; i++) {
        acc[i] += __shfl_xor(acc[i], 16);
        acc[i] += __shfl_xor(acc[i], 32);
    }

    float dv = dinv[w];
    const float4* b4 = (const float4*)bias;
    float4 b0 = b4[sl * 2], b1 = b4[sl * 2 + 1];
    float4 o0, o1;
    o0.x = fmaxf(fmaf(dv, acc[0], b0.x), 0.f);
    o0.y = fmaxf(fmaf(dv, acc[1], b0.y), 0.f);
    o0.z = fmaxf(fmaf(dv, acc[2], b0.z), 0.f);
    o0.w = fmaxf(fmaf(dv, acc[3], b0.w), 0.f);
    o1.x = fmaxf(fmaf(dv, acc[4], b1.x), 0.f);
    o1.y = fmaxf(fmaf(dv, acc[5], b1.y), 0.f);
    o1.z = fmaxf(fmaf(dv, acc[6], b1.z), 0.f);
    o1.w = fmaxf(fmaf(dv, acc[7], b1.w), 0.f);

    if (g == 0) {
        float4* H4 = (float4*)H;
        H4[(size_t)w * 32 + sl * 2]     = o0;
        H4[(size_t)w * 32 + sl * 2 + 1] = o1;
    }
}

// ---------- launch ----------
extern "C" void kernel_launch(void* const* d_in, const int* in_sizes, int n_in,
                              void* d_out, int out_size, void* d_ws, size_t ws_size,
                              hipStream_t stream) {
    const float* x  = (const float*)d_in[0];
    const int*   ei = (const int*)d_in[1];
    const float* W1 = (const float*)d_in[2];
    const float* b1 = (const float*)d_in[3];
    const float* W2 = (const float*)d_in[4];
    const float* b2 = (const float*)d_in[5];
    const float* W3 = (const float*)d_in[6];
    const float* b3 = (const float*)d_in[7];
    const float* Wc = (const float*)d_in[8];
    const float* bc = (const float*)d_in[9];

    const int N = in_sizes[0] / 128;   // 50000
    const int E = in_sizes[1] / 2;     // 800000
    const int* src = ei;
    const int* dst = ei + E;

    // workspace carve-out (~24 MB)
    char* ws = (char*)d_ws;
    size_t off = 0;
    auto alloc = [&](size_t bytes) -> void* {
        void* p = ws + off;
        off = (off + bytes + 255) & ~(size_t)255;
        return p;
    };
    unsigned short* Mbuf = (unsigned short*)alloc((size_t)N * 128 * 2);  // bf16
    unsigned int* pk     = (unsigned int*)alloc((size_t)E * 4);          // bucketed edges
    unsigned short* img  = (unsigned short*)alloc((3 * 32768 + 2 * 6144) * 2);
    float* dinv    = (float*)alloc((size_t)N * 4);
    int*   row_ptr = (int*)alloc((size_t)(N + 1) * 4);
    int*   csr     = (int*)alloc((size_t)E * 4);
    int*   bcnt    = (int*)alloc(256 * 4);
    int*   bofs    = (int*)alloc(257 * 4);
    int*   gcur    = (int*)alloc(256 * 4);
    int*   bsum    = (int*)alloc(256 * 4);

    float* out  = (float*)d_out;               // logits [N,40]
    float* hbuf = out + (size_t)N * 40;        // h region [N,128] — reused for all layers

    const int nb  = (N + 255) / 256;   // 196 (<=256, required by k_scan2)
    const int NB  = (N + 255) >> 8;    // node buckets (196)
    const int G1  = 256;
    const int chunk = (E + G1 - 1) / G1;

    // weight prep (bf16 hi/lo swizzled images) + bcnt zero (block 512)
    k_wprep<<<513, 128, 0, stream>>>(W1, W2, W3, Wc, img, bcnt);

    // CSR build: bucket sort (dst>>8) -> per-bucket degree+scan -> placement
    k_hist<<<G1, 256, 0, stream>>>(dst, E, chunk, bcnt);
    k_bscan<<<1, 256, 0, stream>>>(bcnt, bofs, gcur);
    k_scatter1<<<G1, 256, 0, stream>>>(src, dst, E, chunk, gcur, pk);
    k_degscan<<<NB, 256, 0, stream>>>(pk, bofs, row_ptr, bsum, dinv, N);
    k_scan2<<<1, 256, 0, stream>>>(bsum, nb);
    k_scatter2<<<NB, 256, 0, stream>>>(pk, bofs, row_ptr, bsum, csr, N, E);

    const int gb  = (N + 63) / 64;    // gemm blocks (BM=64)
    const int gab = (N + 3) / 4;      // gather blocks (4 waves/block)

    // layer 1: x -> Mbuf(bf16) -> hbuf
    k_gemm128m<<<gb, 256, 0, stream>>>(x, img, dinv, Mbuf, N);
    k_gather<<<gab, 256, 0, stream>>>(Mbuf, csr, row_ptr, dinv, b1, hbuf, N);
    // layer 2
    k_gemm128m<<<gb, 256, 0, stream>>>(hbuf, img + 32768, dinv, Mbuf, N);
    k_gather<<<gab, 256, 0, stream>>>(Mbuf, csr, row_ptr, dinv, b2, hbuf, N);
    // layer 3: h3 -> d_out h-region
    k_gemm128m<<<gb, 256, 0, stream>>>(hbuf, img + 2 * 32768, dinv, Mbuf, N);
    k_gather<<<gab, 256, 0, stream>>>(Mbuf, csr, row_ptr, dinv, b3, hbuf, N);
    // classifier
    k_gemm40m<<<gb, 256, 0, stream>>>(hbuf, img + 3 * 32768, bc, out, N);
}